// Round 8
// baseline (315.302 us; speedup 1.0000x reference)
//
#include <hip/hip_runtime.h>
#include <math.h>

// Modulated deformable conv v2: B=4, C=256, H=W=64, O=256, K=3, PAD=1
// r25: MEASUREMENT ROUND. Real pipeline = r24b VERBATIM (67.7us, passing).
//      Plus two profiling probes appended after the real kernels, writing
//      only to scratch workspace (the unused former-xlr region):
//        probe_nogather_kernel (rep=5): K3 minus the 32 gathers (replaced by
//          VALU formulas of s_off values). Isolates gather-VMEM cost.
//        probe_nolds_kernel   (rep=4): K3 minus cols-LDS and in-loop
//          barriers (combine feeds MFMA from regs). Isolates the
//          LDS-roundtrip + barrier-lockstep cost.
//      Probes are rep-multiplied so they rank in the top-5 dispatch table.

constexpr int Bn = 4;
constexpr int Cn = 256;
constexpr int Hn = 64;
constexpr int Wn = 64;
constexpr int On = 256;
constexpr int PB = Hn * Wn;     // 4096
constexpr int NCH = 27;

typedef __attribute__((ext_vector_type(8))) _Float16 f16x8;  // 4 VGPRs
typedef __attribute__((ext_vector_type(4))) float f32x4;

union FragU { uint4 u; f16x8 h; };

__device__ inline ushort f2h(float f) {
    _Float16 h = (_Float16)f;
    return __builtin_bit_cast(ushort, h);
}
__device__ inline float hlo(uint u) {
    _Float16 h = __builtin_bit_cast(_Float16, (ushort)(u & 0xffffu));
    return (float)h;
}
__device__ inline float hhi(uint u) {
    _Float16 h = __builtin_bit_cast(_Float16, (ushort)(u >> 16));
    return (float)h;
}
__device__ inline uint pkh(float a, float b) {
    return __builtin_bit_cast(uint, __builtin_amdgcn_cvt_pkrtz(a, b));
}

// ---------------------------------------------------------------- kernel 1
// NCHW fp32 -> NHWC fp16 plane + fp16 weight packs.
__global__ __launch_bounds__(256)
void nhwcpack_kernel(const float* __restrict__ x,
                     const float* __restrict__ w,
                     const float* __restrict__ offw,
                     const float* __restrict__ modw,
                     ushort* __restrict__ xhf,
                     ushort* __restrict__ wTb,
                     ushort* __restrict__ owf)
{
    const int bid = blockIdx.x;
    const int b = bid >> 7, seg = bid & 127;
    const int t = threadIdx.x;
    __shared__ float tile[32][257];

    const float* src = x + (size_t)b * Cn * PB + seg * 32;
    #pragma unroll 4
    for (int i = 0; i < 32; ++i) {
        const int idx = i * 256 + t;
        const int c = idx >> 5, p = idx & 31;
        tile[p][c] = src[(size_t)c * PB + p];
    }
    __syncthreads();

    const int pr = t & 127;
    const int r0 = (t >> 7) * 16;
    uint* dH = reinterpret_cast<uint*>(xhf + ((size_t)b * PB + seg * 32) * 256);
    #pragma unroll 4
    for (int i = 0; i < 16; ++i) {
        const int row = r0 + i;
        const float v0 = tile[row][2 * pr];
        const float v1 = tile[row][2 * pr + 1];
        dH[(size_t)row * 128 + pr] = pkh(v0, v1);
    }

    #pragma unroll 1
    for (int u = 0; u < 5; ++u) {
        int unit = (u < 4) ? bid * 4 + u : (bid < 256 ? 2048 + bid : -1);
        if (unit < 0) break;
        const int tap = unit >> 8, c = unit & 255;
        const int o = t;
        wTb[((size_t)(unit >> 3) * 256 + o) * 8 + (c & 7)] =
            f2h(w[((size_t)o * Cn + c) * 9 + tap]);
        if (o < 32) {
            float v = 0.f;
            if (o < 18)      v = offw[((size_t)o * Cn + c) * 9 + tap];
            else if (o < 27) v = modw[((size_t)(o - 18) * Cn + c) * 9 + tap];
            owf[((size_t)(unit >> 3) * 32 + o) * 8 + (c & 7)] = f2h(v);
        }
    }
}

// ---------------------------------------------------------------- kernel 2
// offset/mask conv, single fp16 plane (r24b).
__global__ __launch_bounds__(512, 2)
void offmask_mfma_kernel(const ushort* __restrict__ xhf,
                         const float* __restrict__ offb,
                         const float* __restrict__ modb,
                         const ushort* __restrict__ owf,
                         float* __restrict__ offm)
{
    const int hw = blockIdx.x;
    const int blk = (hw & 7) * 32 + (hw >> 3);
    const int b = blk >> 6, row = blk & 63;
    const int t = threadIdx.x;
    const int lane = t & 63;
    const int wv  = t >> 6;
    const int l15 = lane & 15;
    const int g   = lane >> 4;
    const int mt  = wv >> 2;
    const int nt  = wv & 3;

    __shared__ uint colsH[8][1024];   // 32 KB

    const ushort* xhb = xhf + (size_t)b * PB * 256;
    const int posT0 = t >> 4;
    const int chq   = t & 15;

    const int ws0 = posT0 * 16
        + 4 * ((chq >> 2) ^ (posT0 & 3) ^ ((posT0 >> 2) & 3)) + (chq & 3);
    const int posT1 = posT0 + 32;
    const int ws1 = posT1 * 16
        + 4 * ((chq >> 2) ^ (posT1 & 3) ^ ((posT1 >> 2) & 3)) + (chq & 3);

    const uint4* owfV = reinterpret_cast<const uint4*>(owf);

    f32x4 acc = (f32x4){0.f, 0.f, 0.f, 0.f};
    const int p = nt * 16 + l15;
    const int ridx = p * 4 + (g ^ (p & 3) ^ ((p >> 2) & 3));

    #pragma unroll 1
    for (int tap = 0; tap < 9; ++tap) {
        const int ty = tap / 3, tx = tap % 3;
        const int y = row - 1 + ty;
        const int xc0 = posT0 - 1 + tx;
        const int xc1 = posT1 - 1 + tx;
        const bool ok0 = (y >= 0) && (y < Hn) && (xc0 >= 0) && (xc0 < Wn);
        const bool ok1 = (y >= 0) && (y < Hn) && (xc1 >= 0) && (xc1 < Wn);
        const int ya  = max(y, 0);
        const int xa0 = min(max(xc0, 0), Wn - 1);
        const int xa1 = min(max(xc1, 0), Wn - 1);
        const size_t p0b = ((size_t)(ya * Wn + xa0)) * 256 + 2 * chq;
        const size_t p1b = ((size_t)(ya * Wn + xa1)) * 256 + 2 * chq;

        uint h0[8], h1[8];
        #pragma unroll
        for (int s = 0; s < 8; ++s) {
            h0[s] = h1[s] = 0u;
            if (ok0) h0[s] = *reinterpret_cast<const uint*>(xhb + p0b + s * 32);
            if (ok1) h1[s] = *reinterpret_cast<const uint*>(xhb + p1b + s * 32);
        }
        uint4 aH[8];
        #pragma unroll
        for (int s = 0; s < 8; ++s) {
            const size_t kb = (size_t)((tap * 8 + s) * 4 + g) * 32 + mt * 16 + l15;
            aH[s] = owfV[kb];
        }

        __syncthreads();

        #pragma unroll
        for (int s = 0; s < 8; ++s) {
            colsH[s][ws0] = h0[s];
            colsH[s][ws1] = h1[s];
        }
        __syncthreads();

        #pragma unroll
        for (int s = 0; s < 8; ++s) {
            FragU aHH, bH;
            aHH.u = aH[s];
            bH.u = reinterpret_cast<const uint4*>(colsH[s])[ridx];
            acc = __builtin_amdgcn_mfma_f32_16x16x32_f16(aHH.h, bH.h, acc, 0, 0, 0);
        }
    }

    const int pos = nt * 16 + l15;
    #pragma unroll
    for (int j = 0; j < 4; ++j) {
        const int ch = mt * 16 + g * 4 + j;
        if (ch < NCH) {
            float v = acc[j];
            if (ch < 18) v += offb[ch];
            else         v = 2.f / (1.f + expf(-(v + modb[ch - 18])));
            offm[((size_t)(b * NCH + ch)) * PB + row * 64 + pos] = v;
        }
    }
}

// ---------------------------------------------------------------- kernel 3
// r24b K3 VERBATIM (real output path).
__global__ __launch_bounds__(512, 2)
void deform_nhwc_kernel(const ushort* __restrict__ xhf,
                        const float* __restrict__ offm,
                        const ushort* __restrict__ wTb,
                        float* __restrict__ out)
{
    const int hw = blockIdx.x;
    const int blk = (hw & 7) * 32 + (hw >> 3);   // XCD swizzle (256 = 8*32)
    const int b = blk >> 6, row = blk & 63;
    const int p0 = row * 64;
    const int t = threadIdx.x;
    const int lane = t & 63;
    const int wv  = t >> 6;
    const int l15 = lane & 15;
    const int g   = lane >> 4;

    __shared__ int4   s_off[576];
    __shared__ float4 s_wgt[576];
    __shared__ uint   cols[4][1024];

    for (int ti = t; ti < 576; ti += 512) {
        const int k = ti >> 6, pos = ti & 63;
        const int p = p0 + pos;
        const float dy = offm[((size_t)(b * NCH + 2 * k)) * PB + p];
        const float dx = offm[((size_t)(b * NCH + 2 * k + 1)) * PB + p];
        const float m  = offm[((size_t)(b * NCH + 18 + k)) * PB + p];
        const int ky = k / 3, kx = k % 3;
        const float py = dy + (float)(ky + row - 1);
        const float px = dx + (float)(kx + pos - 1);
        const float y0f = floorf(py), x0f = floorf(px);
        const float fy = py - y0f, fx = px - x0f;
        const int y0 = (int)y0f, x0i = (int)x0f;
        const int y1 = y0 + 1, x1 = x0i + 1;
        const bool vy0 = (y0 >= 0) && (y0 < Hn);
        const bool vy1 = (y1 >= 0) && (y1 < Hn);
        const bool vx0 = (x0i >= 0) && (x0i < Wn);
        const bool vx1 = (x1 >= 0) && (x1 < Wn);
        const int y0c = min(max(y0, 0), Hn - 1);
        const int y1c = min(max(y1, 0), Hn - 1);
        const int x0c = min(max(x0i, 0), Wn - 1);
        const int x1c = min(max(x1, 0), Wn - 1);
        s_off[ti] = make_int4(y0c * Wn + x0c, y0c * Wn + x1c,
                              y1c * Wn + x0c, y1c * Wn + x1c);
        s_wgt[ti] = make_float4(
            (vy0 && vx0) ? (1.f - fy) * (1.f - fx) * m : 0.f,
            (vy0 && vx1) ? (1.f - fy) * fx * m : 0.f,
            (vy1 && vx0) ? fy * (1.f - fx) * m : 0.f,
            (vy1 && vx1) ? fy * fx * m : 0.f);
    }
    __syncthreads();

    const ushort* xb = xhf + (size_t)b * PB * 256;
    const int posT = t >> 4;
    const int chq  = t & 15;
    const uint4* wvp = reinterpret_cast<const uint4*>(wTb);
    const int o0 = wv * 32;

    const int ws0 = posT * 16
        + 4 * ((chq >> 2) ^ (posT & 3) ^ ((posT >> 2) & 3)) + (chq & 3);

    int ri[4];
    #pragma unroll
    for (int nt = 0; nt < 4; ++nt) {
        const int p = nt * 16 + l15;
        ri[nt] = p * 4 + (g ^ (p & 3) ^ ((p >> 2) & 3));
    }

    f32x4 acc[2][4];
    #pragma unroll
    for (int ot = 0; ot < 2; ++ot)
        #pragma unroll
        for (int nt = 0; nt < 4; ++nt)
            acc[ot][nt] = (f32x4){0.f, 0.f, 0.f, 0.f};

    #pragma unroll 1
    for (int cch = 0; cch < 18; ++cch) {
        const int tap = cch >> 1, cc0 = (cch & 1) * 128;
        const int4   offA = s_off[tap * 64 + posT];
        const float4 wgtA = s_wgt[tap * 64 + posT];
        const int4   offB = s_off[tap * 64 + posT + 32];
        const float4 wgtB = s_wgt[tap * 64 + posT + 32];
        const ushort* xc = xb + cc0 + 2 * chq;

        uint qa[4], qb[4], qc[4], qd[4], ra[4], rb[4], rc[4], rd[4];
        #pragma unroll
        for (int s = 0; s < 4; ++s) {
            const int so = s * 32;
            qa[s] = *reinterpret_cast<const uint*>(xc + (size_t)offA.x * 256 + so);
            qb[s] = *reinterpret_cast<const uint*>(xc + (size_t)offA.y * 256 + so);
            qc[s] = *reinterpret_cast<const uint*>(xc + (size_t)offA.z * 256 + so);
            qd[s] = *reinterpret_cast<const uint*>(xc + (size_t)offA.w * 256 + so);
            ra[s] = *reinterpret_cast<const uint*>(xc + (size_t)offB.x * 256 + so);
            rb[s] = *reinterpret_cast<const uint*>(xc + (size_t)offB.y * 256 + so);
            rc[s] = *reinterpret_cast<const uint*>(xc + (size_t)offB.z * 256 + so);
            rd[s] = *reinterpret_cast<const uint*>(xc + (size_t)offB.w * 256 + so);
        }
        uint4 apre[4][2];
        #pragma unroll
        for (int s = 0; s < 4; ++s) {
            const int kb = (cch * 4 + s) * 4 + g;
            apre[s][0] = wvp[(size_t)kb * 256 + o0 + l15];
            apre[s][1] = wvp[(size_t)kb * 256 + o0 + 16 + l15];
        }

        __syncthreads();

        #pragma unroll
        for (int s = 0; s < 4; ++s) {
            const float v0 = wgtA.x * hlo(qa[s]) + wgtA.y * hlo(qb[s])
                           + wgtA.z * hlo(qc[s]) + wgtA.w * hlo(qd[s]);
            const float v1 = wgtA.x * hhi(qa[s]) + wgtA.y * hhi(qb[s])
                           + wgtA.z * hhi(qc[s]) + wgtA.w * hhi(qd[s]);
            cols[s][ws0] = pkh(v0, v1);
            const float u0 = wgtB.x * hlo(ra[s]) + wgtB.y * hlo(rb[s])
                           + wgtB.z * hlo(rc[s]) + wgtB.w * hlo(rd[s]);
            const float u1 = wgtB.x * hhi(ra[s]) + wgtB.y * hhi(rb[s])
                           + wgtB.z * hhi(rc[s]) + wgtB.w * hhi(rd[s]);
            cols[s][ws0 + 512] = pkh(u0, u1);
        }
        __syncthreads();

        #pragma unroll
        for (int s = 0; s < 4; ++s) {
            FragU a0, a1, bf[4];
            a0.u = apre[s][0]; a1.u = apre[s][1];
            #pragma unroll
            for (int nt = 0; nt < 4; ++nt)
                bf[nt].u = reinterpret_cast<const uint4*>(cols[s])[ri[nt]];
            #pragma unroll
            for (int nt = 0; nt < 4; ++nt) {
                acc[0][nt] = __builtin_amdgcn_mfma_f32_16x16x32_f16(
                    a0.h, bf[nt].h, acc[0][nt], 0, 0, 0);
                acc[1][nt] = __builtin_amdgcn_mfma_f32_16x16x32_f16(
                    a1.h, bf[nt].h, acc[1][nt], 0, 0, 0);
            }
        }
    }

    float* ob = out + (size_t)b * On * PB;
    #pragma unroll
    for (int ot = 0; ot < 2; ++ot)
        #pragma unroll
        for (int nt = 0; nt < 4; ++nt)
            #pragma unroll
            for (int j = 0; j < 4; ++j)
                ob[((size_t)(o0 + ot * 16 + g * 4 + j)) * PB
                   + p0 + nt * 16 + l15] = acc[ot][nt][j];
}

// ---------------------------------------------------------------- probe A
// K3 minus gathers (VALU formulas of s_off values). rep=5. Scratch output.
__global__ __launch_bounds__(512, 2)
void probe_nogather_kernel(const ushort* __restrict__ xhf,
                           const float* __restrict__ offm,
                           const ushort* __restrict__ wTb,
                           float* __restrict__ scratch)
{
    const int hw = blockIdx.x;
    const int blk = (hw & 7) * 32 + (hw >> 3);
    const int b = blk >> 6, row = blk & 63;
    const int p0 = row * 64;
    const int t = threadIdx.x;
    const int lane = t & 63;
    const int wv  = t >> 6;
    const int l15 = lane & 15;
    const int g   = lane >> 4;

    __shared__ int4   s_off[576];
    __shared__ float4 s_wgt[576];
    __shared__ uint   cols[4][1024];

    for (int ti = t; ti < 576; ti += 512) {
        const int k = ti >> 6, pos = ti & 63;
        const int p = p0 + pos;
        const float dy = offm[((size_t)(b * NCH + 2 * k)) * PB + p];
        const float dx = offm[((size_t)(b * NCH + 2 * k + 1)) * PB + p];
        const float m  = offm[((size_t)(b * NCH + 18 + k)) * PB + p];
        const int ky = k / 3, kx = k % 3;
        const float py = dy + (float)(ky + row - 1);
        const float px = dx + (float)(kx + pos - 1);
        const float y0f = floorf(py), x0f = floorf(px);
        const float fy = py - y0f, fx = px - x0f;
        const int y0 = (int)y0f, x0i = (int)x0f;
        const int y1 = y0 + 1, x1 = x0i + 1;
        const bool vy0 = (y0 >= 0) && (y0 < Hn);
        const bool vy1 = (y1 >= 0) && (y1 < Hn);
        const bool vx0 = (x0i >= 0) && (x0i < Wn);
        const bool vx1 = (x1 >= 0) && (x1 < Wn);
        const int y0c = min(max(y0, 0), Hn - 1);
        const int y1c = min(max(y1, 0), Hn - 1);
        const int x0c = min(max(x0i, 0), Wn - 1);
        const int x1c = min(max(x1, 0), Wn - 1);
        s_off[ti] = make_int4(y0c * Wn + x0c, y0c * Wn + x1c,
                              y1c * Wn + x0c, y1c * Wn + x1c);
        s_wgt[ti] = make_float4(
            (vy0 && vx0) ? (1.f - fy) * (1.f - fx) * m : 0.f,
            (vy0 && vx1) ? (1.f - fy) * fx * m : 0.f,
            (vy1 && vx0) ? fy * (1.f - fx) * m : 0.f,
            (vy1 && vx1) ? fy * fx * m : 0.f);
    }
    __syncthreads();

    const int posT = t >> 4;
    const int chq  = t & 15;
    const uint4* wvp = reinterpret_cast<const uint4*>(wTb);
    const int o0 = wv * 32;

    const int ws0 = posT * 16
        + 4 * ((chq >> 2) ^ (posT & 3) ^ ((posT >> 2) & 3)) + (chq & 3);

    int ri[4];
    #pragma unroll
    for (int nt = 0; nt < 4; ++nt) {
        const int p = nt * 16 + l15;
        ri[nt] = p * 4 + (g ^ (p & 3) ^ ((p >> 2) & 3));
    }

    f32x4 acc[2][4];
    #pragma unroll
    for (int ot = 0; ot < 2; ++ot)
        #pragma unroll
        for (int nt = 0; nt < 4; ++nt)
            acc[ot][nt] = (f32x4){0.f, 0.f, 0.f, 0.f};

    #pragma unroll 1
    for (int rep = 0; rep < 5; ++rep) {
        int repq = rep;
        asm volatile("" : "+v"(repq));          // opaque; prevents LICM
        const int rbump = repq >> 9;            // always 0

        #pragma unroll 1
        for (int cch = 0; cch < 18; ++cch) {
            const int tap = cch >> 1;
            const int4   offA = s_off[tap * 64 + posT];
            const float4 wgtA = s_wgt[tap * 64 + posT];
            const int4   offB = s_off[tap * 64 + posT + 32];
            const float4 wgtB = s_wgt[tap * 64 + posT + 32];

            // --- gathers replaced by formulas (keeps s_off dependency) ---
            uint qa[4], qb[4], qc[4], qd[4], ra[4], rb[4], rc[4], rd[4];
            #pragma unroll
            for (int s = 0; s < 4; ++s) {
                qa[s] = (uint)(offA.x + s * 3 + cch);
                qb[s] = (uint)(offA.y + s * 5 + cch);
                qc[s] = (uint)(offA.z + s * 7 + cch);
                qd[s] = (uint)(offA.w + s * 9 + cch);
                ra[s] = (uint)(offB.x + s * 3 + cch);
                rb[s] = (uint)(offB.y + s * 5 + cch);
                rc[s] = (uint)(offB.z + s * 7 + cch);
                rd[s] = (uint)(offB.w + s * 9 + cch);
            }
            uint4 apre[4][2];
            #pragma unroll
            for (int s = 0; s < 4; ++s) {
                const int kb = (cch * 4 + s) * 4 + g + rbump;
                apre[s][0] = wvp[(size_t)kb * 256 + o0 + l15];
                apre[s][1] = wvp[(size_t)kb * 256 + o0 + 16 + l15];
            }

            __syncthreads();

            #pragma unroll
            for (int s = 0; s < 4; ++s) {
                const float v0 = wgtA.x * hlo(qa[s]) + wgtA.y * hlo(qb[s])
                               + wgtA.z * hlo(qc[s]) + wgtA.w * hlo(qd[s]);
                const float v1 = wgtA.x * hhi(qa[s]) + wgtA.y * hhi(qb[s])
                               + wgtA.z * hhi(qc[s]) + wgtA.w * hhi(qd[s]);
                cols[s][ws0] = pkh(v0, v1);
                const float u0 = wgtB.x * hlo(ra[s]) + wgtB.y * hlo(rb[s])
                               + wgtB.z * hlo(rc[s]) + wgtB.w * hlo(rd[s]);
                const float u1 = wgtB.x * hhi(ra[s]) + wgtB.y * hhi(rb[s])
                               + wgtB.z * hhi(rc[s]) + wgtB.w * hhi(rd[s]);
                cols[s][ws0 + 512] = pkh(u0, u1);
            }
            __syncthreads();

            #pragma unroll
            for (int s = 0; s < 4; ++s) {
                FragU a0, a1, bf[4];
                a0.u = apre[s][0]; a1.u = apre[s][1];
                #pragma unroll
                for (int nt = 0; nt < 4; ++nt)
                    bf[nt].u = reinterpret_cast<const uint4*>(cols[s])[ri[nt]];
                #pragma unroll
                for (int nt = 0; nt < 4; ++nt) {
                    acc[0][nt] = __builtin_amdgcn_mfma_f32_16x16x32_f16(
                        a0.h, bf[nt].h, acc[0][nt], 0, 0, 0);
                    acc[1][nt] = __builtin_amdgcn_mfma_f32_16x16x32_f16(
                        a1.h, bf[nt].h, acc[1][nt], 0, 0, 0);
                }
            }
        }
    }

    #pragma unroll
    for (int ot = 0; ot < 2; ++ot)
        #pragma unroll
        for (int nt = 0; nt < 4; ++nt)
            #pragma unroll
            for (int j = 0; j < 4; ++j) {
                const size_t idx = ((size_t)(o0 + ot * 16 + g * 4 + j)) * PB
                                   + p0 + nt * 16 + l15;
                scratch[idx & 0x1FFFFF] = acc[ot][nt][j];
            }
}

// ---------------------------------------------------------------- probe B
// K3 minus cols-LDS and in-loop barriers (reg-direct MFMA feed). rep=4.
__global__ __launch_bounds__(512, 2)
void probe_nolds_kernel(const ushort* __restrict__ xhf,
                        const float* __restrict__ offm,
                        const ushort* __restrict__ wTb,
                        float* __restrict__ scratch)
{
    const int hw = blockIdx.x;
    const int blk = (hw & 7) * 32 + (hw >> 3);
    const int b = blk >> 6, row = blk & 63;
    const int p0 = row * 64;
    const int t = threadIdx.x;
    const int lane = t & 63;
    const int wv  = t >> 6;
    const int l15 = lane & 15;
    const int g   = lane >> 4;

    __shared__ int4   s_off[576];
    __shared__ float4 s_wgt[576];

    for (int ti = t; ti < 576; ti += 512) {
        const int k = ti >> 6, pos = ti & 63;
        const int p = p0 + pos;
        const float dy = offm[((size_t)(b * NCH + 2 * k)) * PB + p];
        const float dx = offm[((size_t)(b * NCH + 2 * k + 1)) * PB + p];
        const float m  = offm[((size_t)(b * NCH + 18 + k)) * PB + p];
        const int ky = k / 3, kx = k % 3;
        const float py = dy + (float)(ky + row - 1);
        const float px = dx + (float)(kx + pos - 1);
        const float y0f = floorf(py), x0f = floorf(px);
        const float fy = py - y0f, fx = px - x0f;
        const int y0 = (int)y0f, x0i = (int)x0f;
        const int y1 = y0 + 1, x1 = x0i + 1;
        const bool vy0 = (y0 >= 0) && (y0 < Hn);
        const bool vy1 = (y1 >= 0) && (y1 < Hn);
        const bool vx0 = (x0i >= 0) && (x0i < Wn);
        const bool vx1 = (x1 >= 0) && (x1 < Wn);
        const int y0c = min(max(y0, 0), Hn - 1);
        const int y1c = min(max(y1, 0), Hn - 1);
        const int x0c = min(max(x0i, 0), Wn - 1);
        const int x1c = min(max(x1, 0), Wn - 1);
        s_off[ti] = make_int4(y0c * Wn + x0c, y0c * Wn + x1c,
                              y1c * Wn + x0c, y1c * Wn + x1c);
        s_wgt[ti] = make_float4(
            (vy0 && vx0) ? (1.f - fy) * (1.f - fx) * m : 0.f,
            (vy0 && vx1) ? (1.f - fy) * fx * m : 0.f,
            (vy1 && vx0) ? fy * (1.f - fx) * m : 0.f,
            (vy1 && vx1) ? fy * fx * m : 0.f);
    }
    __syncthreads();   // table barrier only; NO barriers in main loop

    const ushort* xb = xhf + (size_t)b * PB * 256;
    const int posT = t >> 4;
    const int chq  = t & 15;
    const uint4* wvp = reinterpret_cast<const uint4*>(wTb);
    const int o0 = wv * 32;

    f32x4 acc[2][4];
    #pragma unroll
    for (int ot = 0; ot < 2; ++ot)
        #pragma unroll
        for (int nt = 0; nt < 4; ++nt)
            acc[ot][nt] = (f32x4){0.f, 0.f, 0.f, 0.f};

    #pragma unroll 1
    for (int rep = 0; rep < 4; ++rep) {
        int repq = rep;
        asm volatile("" : "+v"(repq));
        const int rbump = repq >> 9;            // always 0

        #pragma unroll 1
        for (int cch = 0; cch < 18; ++cch) {
            const int tap = cch >> 1, cc0 = (cch & 1) * 128;
            const int4   offA = s_off[tap * 64 + posT];
            const float4 wgtA = s_wgt[tap * 64 + posT];
            const int4   offB = s_off[tap * 64 + posT + 32];
            const float4 wgtB = s_wgt[tap * 64 + posT + 32];
            const ushort* xc = xb + cc0 + 2 * chq + rbump;

            uint qa[4], qb[4], qc[4], qd[4], ra[4], rb[4], rc[4], rd[4];
            #pragma unroll
            for (int s = 0; s < 4; ++s) {
                const int so = s * 32;
                qa[s] = *reinterpret_cast<const uint*>(xc + (size_t)offA.x * 256 + so);
                qb[s] = *reinterpret_cast<const uint*>(xc + (size_t)offA.y * 256 + so);
                qc[s] = *reinterpret_cast<const uint*>(xc + (size_t)offA.z * 256 + so);
                qd[s] = *reinterpret_cast<const uint*>(xc + (size_t)offA.w * 256 + so);
                ra[s] = *reinterpret_cast<const uint*>(xc + (size_t)offB.x * 256 + so);
                rb[s] = *reinterpret_cast<const uint*>(xc + (size_t)offB.y * 256 + so);
                rc[s] = *reinterpret_cast<const uint*>(xc + (size_t)offB.z * 256 + so);
                rd[s] = *reinterpret_cast<const uint*>(xc + (size_t)offB.w * 256 + so);
            }
            uint4 apre[4][2];
            #pragma unroll
            for (int s = 0; s < 4; ++s) {
                const int kb = (cch * 4 + s) * 4 + g + rbump;
                apre[s][0] = wvp[(size_t)kb * 256 + o0 + l15];
                apre[s][1] = wvp[(size_t)kb * 256 + o0 + 16 + l15];
            }

            // combine -> registers (same VALU as real)
            uint c0[4], c1[4];
            #pragma unroll
            for (int s = 0; s < 4; ++s) {
                const float v0 = wgtA.x * hlo(qa[s]) + wgtA.y * hlo(qb[s])
                               + wgtA.z * hlo(qc[s]) + wgtA.w * hlo(qd[s]);
                const float v1 = wgtA.x * hhi(qa[s]) + wgtA.y * hhi(qb[s])
                               + wgtA.z * hhi(qc[s]) + wgtA.w * hhi(qd[s]);
                c0[s] = pkh(v0, v1);
                const float u0 = wgtB.x * hlo(ra[s]) + wgtB.y * hlo(rb[s])
                               + wgtB.z * hlo(rc[s]) + wgtB.w * hlo(rd[s]);
                const float u1 = wgtB.x * hhi(ra[s]) + wgtB.y * hhi(rb[s])
                               + wgtB.z * hhi(rc[s]) + wgtB.w * hhi(rd[s]);
                c1[s] = pkh(u0, u1);
            }

            // MFMA feed directly from regs (wrong layout, right inst mix)
            #pragma unroll
            for (int s = 0; s < 4; ++s) {
                FragU a0, a1, bfr;
                a0.u = apre[s][0]; a1.u = apre[s][1];
                bfr.u = make_uint4(c0[s], c1[s], c0[s], c1[s]);
                #pragma unroll
                for (int nt = 0; nt < 4; ++nt) {
                    acc[0][nt] = __builtin_amdgcn_mfma_f32_16x16x32_f16(
                        a0.h, bfr.h, acc[0][nt], 0, 0, 0);
                    acc[1][nt] = __builtin_amdgcn_mfma_f32_16x16x32_f16(
                        a1.h, bfr.h, acc[1][nt], 0, 0, 0);
                }
            }
        }
    }

    #pragma unroll
    for (int ot = 0; ot < 2; ++ot)
        #pragma unroll
        for (int nt = 0; nt < 4; ++nt)
            #pragma unroll
            for (int j = 0; j < 4; ++j) {
                const size_t idx = ((size_t)(o0 + ot * 16 + g * 4 + j)) * PB
                                   + p0 + nt * 16 + l15;
                scratch[idx & 0x1FFFFF] = acc[ot][nt][j];
            }
}

// ---------------------------------------------------------------- launch
extern "C" void kernel_launch(void* const* d_in, const int* in_sizes, int n_in,
                              void* d_out, int out_size, void* d_ws, size_t ws_size,
                              hipStream_t stream)
{
    const float* x    = (const float*)d_in[0];
    const float* offw = (const float*)d_in[1];
    const float* offb = (const float*)d_in[2];
    const float* modw = (const float*)d_in[3];
    const float* modb = (const float*)d_in[4];
    const float* wgt  = (const float*)d_in[5];
    float* out = (float*)d_out;

    char* ws = (char*)d_ws;
    float*  offm = (float*)ws;                   // 1,769,472 B
    ushort* wTb  = (ushort*)(ws + 1769472);      // 1,179,648 B
    ushort* owf  = (ushort*)(ws + 2949120);      // 147,456 B
    ushort* xhf  = (ushort*)(ws + 3244032);      // 8,388,608 B (fp16 NHWC)
    float*  scr  = (float*)(ws + 11632640);      // 8,388,608 B scratch (probes)

    nhwcpack_kernel<<<dim3(512), dim3(256), 0, stream>>>(
        x, wgt, offw, modw, xhf, wTb, owf);
    offmask_mfma_kernel<<<dim3(256), dim3(512), 0, stream>>>(
        xhf, offb, modb, owf, offm);
    deform_nhwc_kernel<<<dim3(256), dim3(512), 0, stream>>>(
        xhf, offm, wTb, out);

    // ---- profiling probes (scratch only; do not affect correctness) ----
    probe_nogather_kernel<<<dim3(256), dim3(512), 0, stream>>>(
        xhf, offm, wTb, scr);
    probe_nolds_kernel<<<dim3(256), dim3(512), 0, stream>>>(
        xhf, offm, wTb, scr);
}

// Round 9
// 69.435 us; speedup vs baseline: 4.5410x; 4.5410x over previous
//
#include <hip/hip_runtime.h>
#include <math.h>

// Modulated deformable conv v2: B=4, C=256, H=W=64, O=256, K=3, PAD=1
// r26: PACKED-FP16 COMBINE in K3 (probe-driven: r25 showed gather-free
//      structure = 31.5us of K3's 47us, VALUBusy 46% -> combine VALU is the
//      biggest slice). Bilinear blend now uses v_pk_fma_f16 on packed pairs
//      (4 ops/pair vs ~17), weights pre-duplicated as fp16 lane-pairs in the
//      tap table. Everything else = r24b verbatim (67.7us baseline).

constexpr int Bn = 4;
constexpr int Cn = 256;
constexpr int Hn = 64;
constexpr int Wn = 64;
constexpr int On = 256;
constexpr int PB = Hn * Wn;     // 4096
constexpr int NCH = 27;

typedef __attribute__((ext_vector_type(8))) _Float16 f16x8;  // 4 VGPRs
typedef __attribute__((ext_vector_type(2))) _Float16 f16x2;
typedef __attribute__((ext_vector_type(4))) float f32x4;

union FragU { uint4 u; f16x8 h; };

__device__ inline ushort f2h(float f) {
    _Float16 h = (_Float16)f;
    return __builtin_bit_cast(ushort, h);
}
__device__ inline uint pkh(float a, float b) {
    return __builtin_bit_cast(uint, __builtin_amdgcn_cvt_pkrtz(a, b));
}
__device__ inline f16x2 u2h(uint u) { return __builtin_bit_cast(f16x2, u); }
__device__ inline uint h2u(f16x2 h) { return __builtin_bit_cast(uint, h); }

// ---------------------------------------------------------------- kernel 1
// NCHW fp32 -> NHWC fp16 plane + fp16 weight packs (r24b verbatim).
__global__ __launch_bounds__(256)
void nhwcpack_kernel(const float* __restrict__ x,
                     const float* __restrict__ w,
                     const float* __restrict__ offw,
                     const float* __restrict__ modw,
                     ushort* __restrict__ xhf,
                     ushort* __restrict__ wTb,
                     ushort* __restrict__ owf)
{
    const int bid = blockIdx.x;
    const int b = bid >> 7, seg = bid & 127;
    const int t = threadIdx.x;
    __shared__ float tile[32][257];

    const float* src = x + (size_t)b * Cn * PB + seg * 32;
    #pragma unroll 4
    for (int i = 0; i < 32; ++i) {
        const int idx = i * 256 + t;
        const int c = idx >> 5, p = idx & 31;
        tile[p][c] = src[(size_t)c * PB + p];
    }
    __syncthreads();

    const int pr = t & 127;
    const int r0 = (t >> 7) * 16;
    uint* dH = reinterpret_cast<uint*>(xhf + ((size_t)b * PB + seg * 32) * 256);
    #pragma unroll 4
    for (int i = 0; i < 16; ++i) {
        const int row = r0 + i;
        const float v0 = tile[row][2 * pr];
        const float v1 = tile[row][2 * pr + 1];
        dH[(size_t)row * 128 + pr] = pkh(v0, v1);
    }

    #pragma unroll 1
    for (int u = 0; u < 5; ++u) {
        int unit = (u < 4) ? bid * 4 + u : (bid < 256 ? 2048 + bid : -1);
        if (unit < 0) break;
        const int tap = unit >> 8, c = unit & 255;
        const int o = t;
        wTb[((size_t)(unit >> 3) * 256 + o) * 8 + (c & 7)] =
            f2h(w[((size_t)o * Cn + c) * 9 + tap]);
        if (o < 32) {
            float v = 0.f;
            if (o < 18)      v = offw[((size_t)o * Cn + c) * 9 + tap];
            else if (o < 27) v = modw[((size_t)(o - 18) * Cn + c) * 9 + tap];
            owf[((size_t)(unit >> 3) * 32 + o) * 8 + (c & 7)] = f2h(v);
        }
    }
}

// ---------------------------------------------------------------- kernel 2
// offset/mask conv, single fp16 plane (r24b verbatim).
__global__ __launch_bounds__(512, 2)
void offmask_mfma_kernel(const ushort* __restrict__ xhf,
                         const float* __restrict__ offb,
                         const float* __restrict__ modb,
                         const ushort* __restrict__ owf,
                         float* __restrict__ offm)
{
    const int hw = blockIdx.x;
    const int blk = (hw & 7) * 32 + (hw >> 3);
    const int b = blk >> 6, row = blk & 63;
    const int t = threadIdx.x;
    const int lane = t & 63;
    const int wv  = t >> 6;
    const int l15 = lane & 15;
    const int g   = lane >> 4;
    const int mt  = wv >> 2;
    const int nt  = wv & 3;

    __shared__ uint colsH[8][1024];   // 32 KB

    const ushort* xhb = xhf + (size_t)b * PB * 256;
    const int posT0 = t >> 4;
    const int chq   = t & 15;

    const int ws0 = posT0 * 16
        + 4 * ((chq >> 2) ^ (posT0 & 3) ^ ((posT0 >> 2) & 3)) + (chq & 3);
    const int posT1 = posT0 + 32;
    const int ws1 = posT1 * 16
        + 4 * ((chq >> 2) ^ (posT1 & 3) ^ ((posT1 >> 2) & 3)) + (chq & 3);

    const uint4* owfV = reinterpret_cast<const uint4*>(owf);

    f32x4 acc = (f32x4){0.f, 0.f, 0.f, 0.f};
    const int p = nt * 16 + l15;
    const int ridx = p * 4 + (g ^ (p & 3) ^ ((p >> 2) & 3));

    #pragma unroll 1
    for (int tap = 0; tap < 9; ++tap) {
        const int ty = tap / 3, tx = tap % 3;
        const int y = row - 1 + ty;
        const int xc0 = posT0 - 1 + tx;
        const int xc1 = posT1 - 1 + tx;
        const bool ok0 = (y >= 0) && (y < Hn) && (xc0 >= 0) && (xc0 < Wn);
        const bool ok1 = (y >= 0) && (y < Hn) && (xc1 >= 0) && (xc1 < Wn);
        const int ya  = max(y, 0);
        const int xa0 = min(max(xc0, 0), Wn - 1);
        const int xa1 = min(max(xc1, 0), Wn - 1);
        const size_t p0b = ((size_t)(ya * Wn + xa0)) * 256 + 2 * chq;
        const size_t p1b = ((size_t)(ya * Wn + xa1)) * 256 + 2 * chq;

        uint h0[8], h1[8];
        #pragma unroll
        for (int s = 0; s < 8; ++s) {
            h0[s] = h1[s] = 0u;
            if (ok0) h0[s] = *reinterpret_cast<const uint*>(xhb + p0b + s * 32);
            if (ok1) h1[s] = *reinterpret_cast<const uint*>(xhb + p1b + s * 32);
        }
        uint4 aH[8];
        #pragma unroll
        for (int s = 0; s < 8; ++s) {
            const size_t kb = (size_t)((tap * 8 + s) * 4 + g) * 32 + mt * 16 + l15;
            aH[s] = owfV[kb];
        }

        __syncthreads();

        #pragma unroll
        for (int s = 0; s < 8; ++s) {
            colsH[s][ws0] = h0[s];
            colsH[s][ws1] = h1[s];
        }
        __syncthreads();

        #pragma unroll
        for (int s = 0; s < 8; ++s) {
            FragU aHH, bH;
            aHH.u = aH[s];
            bH.u = reinterpret_cast<const uint4*>(colsH[s])[ridx];
            acc = __builtin_amdgcn_mfma_f32_16x16x32_f16(aHH.h, bH.h, acc, 0, 0, 0);
        }
    }

    const int pos = nt * 16 + l15;
    #pragma unroll
    for (int j = 0; j < 4; ++j) {
        const int ch = mt * 16 + g * 4 + j;
        if (ch < NCH) {
            float v = acc[j];
            if (ch < 18) v += offb[ch];
            else         v = 2.f / (1.f + expf(-(v + modb[ch - 18])));
            offm[((size_t)(b * NCH + ch)) * PB + row * 64 + pos] = v;
        }
    }
}

// ---------------------------------------------------------------- kernel 3
// r24b frame; combine rewritten to packed fp16 (v_pk_fma_f16), weights
// pre-duplicated in the tap table as fp16 lane-pairs.
__global__ __launch_bounds__(512, 2)
void deform_nhwc_kernel(const ushort* __restrict__ xhf,
                        const float* __restrict__ offm,
                        const ushort* __restrict__ wTb,
                        float* __restrict__ out)
{
    const int hw = blockIdx.x;
    const int blk = (hw & 7) * 32 + (hw >> 3);   // XCD swizzle (256 = 8*32)
    const int b = blk >> 6, row = blk & 63;
    const int p0 = row * 64;
    const int t = threadIdx.x;
    const int lane = t & 63;
    const int wv  = t >> 6;
    const int l15 = lane & 15;
    const int g   = lane >> 4;

    __shared__ int4  s_off[576];       // [tap][pos 0..63]
    __shared__ uint4 s_wgt[576];       // duplicated-fp16 weight pairs
    __shared__ uint  cols[4][1024];    // [step][pos*16+slot] (16 KB)

    for (int ti = t; ti < 576; ti += 512) {
        const int k = ti >> 6, pos = ti & 63;
        const int p = p0 + pos;
        const float dy = offm[((size_t)(b * NCH + 2 * k)) * PB + p];
        const float dx = offm[((size_t)(b * NCH + 2 * k + 1)) * PB + p];
        const float m  = offm[((size_t)(b * NCH + 18 + k)) * PB + p];
        const int ky = k / 3, kx = k % 3;
        const float py = dy + (float)(ky + row - 1);
        const float px = dx + (float)(kx + pos - 1);
        const float y0f = floorf(py), x0f = floorf(px);
        const float fy = py - y0f, fx = px - x0f;
        const int y0 = (int)y0f, x0i = (int)x0f;
        const int y1 = y0 + 1, x1 = x0i + 1;
        const bool vy0 = (y0 >= 0) && (y0 < Hn);
        const bool vy1 = (y1 >= 0) && (y1 < Hn);
        const bool vx0 = (x0i >= 0) && (x0i < Wn);
        const bool vx1 = (x1 >= 0) && (x1 < Wn);
        const int y0c = min(max(y0, 0), Hn - 1);
        const int y1c = min(max(y1, 0), Hn - 1);
        const int x0c = min(max(x0i, 0), Wn - 1);
        const int x1c = min(max(x1, 0), Wn - 1);
        s_off[ti] = make_int4(y0c * Wn + x0c, y0c * Wn + x1c,
                              y1c * Wn + x0c, y1c * Wn + x1c);
        const float w0 = (vy0 && vx0) ? (1.f - fy) * (1.f - fx) * m : 0.f;
        const float w1 = (vy0 && vx1) ? (1.f - fy) * fx * m : 0.f;
        const float w2 = (vy1 && vx0) ? fy * (1.f - fx) * m : 0.f;
        const float w3 = (vy1 && vx1) ? fy * fx * m : 0.f;
        s_wgt[ti] = make_uint4(pkh(w0, w0), pkh(w1, w1),
                               pkh(w2, w2), pkh(w3, w3));
    }
    __syncthreads();   // tap tables visible before ANY gather

    const ushort* xb = xhf + (size_t)b * PB * 256;
    const int posT = t >> 4;       // 0..31; this thread stages posT and posT+32
    const int chq  = t & 15;
    const uint4* wvp = reinterpret_cast<const uint4*>(wTb);
    const int o0 = wv * 32;

    const int ws0 = posT * 16
        + 4 * ((chq >> 2) ^ (posT & 3) ^ ((posT >> 2) & 3)) + (chq & 3);
    // posT+32: low bits of pos identical -> slot = ws0 + 512

    int ri[4];
    #pragma unroll
    for (int nt = 0; nt < 4; ++nt) {
        const int p = nt * 16 + l15;
        ri[nt] = p * 4 + (g ^ (p & 3) ^ ((p >> 2) & 3));
    }

    f32x4 acc[2][4];
    #pragma unroll
    for (int ot = 0; ot < 2; ++ot)
        #pragma unroll
        for (int nt = 0; nt < 4; ++nt)
            acc[ot][nt] = (f32x4){0.f, 0.f, 0.f, 0.f};

    #pragma unroll 1
    for (int cch = 0; cch < 18; ++cch) {
        const int tap = cch >> 1, cc0 = (cch & 1) * 128;
        const int4  offA = s_off[tap * 64 + posT];
        const uint4 wgtA = s_wgt[tap * 64 + posT];
        const int4  offB = s_off[tap * 64 + posT + 32];
        const uint4 wgtB = s_wgt[tap * 64 + posT + 32];
        const ushort* xc = xb + cc0 + 2 * chq;

        // ---- issue 32 fp16 gathers (2 pos x 4 corners x 4 steps) + 8 A-loads
        uint qa[4], qb[4], qc[4], qd[4], ra[4], rb[4], rc[4], rd[4];
        #pragma unroll
        for (int s = 0; s < 4; ++s) {
            const int so = s * 32;
            qa[s] = *reinterpret_cast<const uint*>(xc + (size_t)offA.x * 256 + so);
            qb[s] = *reinterpret_cast<const uint*>(xc + (size_t)offA.y * 256 + so);
            qc[s] = *reinterpret_cast<const uint*>(xc + (size_t)offA.z * 256 + so);
            qd[s] = *reinterpret_cast<const uint*>(xc + (size_t)offA.w * 256 + so);
            ra[s] = *reinterpret_cast<const uint*>(xc + (size_t)offB.x * 256 + so);
            rb[s] = *reinterpret_cast<const uint*>(xc + (size_t)offB.y * 256 + so);
            rc[s] = *reinterpret_cast<const uint*>(xc + (size_t)offB.z * 256 + so);
            rd[s] = *reinterpret_cast<const uint*>(xc + (size_t)offB.w * 256 + so);
        }
        uint4 apre[4][2];
        #pragma unroll
        for (int s = 0; s < 4; ++s) {
            const int kb = (cch * 4 + s) * 4 + g;
            apre[s][0] = wvp[(size_t)kb * 256 + o0 + l15];
            apre[s][1] = wvp[(size_t)kb * 256 + o0 + 16 + l15];
        }

        __syncthreads();   // prior chunk's MFMA reads complete before overwrite

        // ---- packed fp16 bilinear combine: 4 pk ops per pair ----
        #pragma unroll
        for (int s = 0; s < 4; ++s) {
            f16x2 v = u2h(qa[s]) * u2h(wgtA.x);
            v += u2h(qb[s]) * u2h(wgtA.y);
            v += u2h(qc[s]) * u2h(wgtA.z);
            v += u2h(qd[s]) * u2h(wgtA.w);
            cols[s][ws0] = h2u(v);
            f16x2 u = u2h(ra[s]) * u2h(wgtB.x);
            u += u2h(rb[s]) * u2h(wgtB.y);
            u += u2h(rc[s]) * u2h(wgtB.z);
            u += u2h(rd[s]) * u2h(wgtB.w);
            cols[s][ws0 + 512] = h2u(u);
        }
        __syncthreads();   // writes visible before MFMA reads

        #pragma unroll
        for (int s = 0; s < 4; ++s) {
            FragU a0, a1, bf[4];
            a0.u = apre[s][0]; a1.u = apre[s][1];
            #pragma unroll
            for (int nt = 0; nt < 4; ++nt)
                bf[nt].u = reinterpret_cast<const uint4*>(cols[s])[ri[nt]];
            #pragma unroll
            for (int nt = 0; nt < 4; ++nt) {
                acc[0][nt] = __builtin_amdgcn_mfma_f32_16x16x32_f16(
                    a0.h, bf[nt].h, acc[0][nt], 0, 0, 0);
                acc[1][nt] = __builtin_amdgcn_mfma_f32_16x16x32_f16(
                    a1.h, bf[nt].h, acc[1][nt], 0, 0, 0);
            }
        }
    }

    float* ob = out + (size_t)b * On * PB;
    #pragma unroll
    for (int ot = 0; ot < 2; ++ot)
        #pragma unroll
        for (int nt = 0; nt < 4; ++nt)
            #pragma unroll
            for (int j = 0; j < 4; ++j)
                ob[((size_t)(o0 + ot * 16 + g * 4 + j)) * PB
                   + p0 + nt * 16 + l15] = acc[ot][nt][j];
}

// ---------------------------------------------------------------- launch
extern "C" void kernel_launch(void* const* d_in, const int* in_sizes, int n_in,
                              void* d_out, int out_size, void* d_ws, size_t ws_size,
                              hipStream_t stream)
{
    const float* x    = (const float*)d_in[0];
    const float* offw = (const float*)d_in[1];
    const float* offb = (const float*)d_in[2];
    const float* modw = (const float*)d_in[3];
    const float* modb = (const float*)d_in[4];
    const float* wgt  = (const float*)d_in[5];
    float* out = (float*)d_out;

    char* ws = (char*)d_ws;
    float*  offm = (float*)ws;                   // 1,769,472 B
    ushort* wTb  = (ushort*)(ws + 1769472);      // 1,179,648 B
    ushort* owf  = (ushort*)(ws + 2949120);      // 147,456 B
    ushort* xhf  = (ushort*)(ws + 3244032);      // 8,388,608 B (fp16 NHWC)

    nhwcpack_kernel<<<dim3(512), dim3(256), 0, stream>>>(
        x, wgt, offw, modw, xhf, wTb, owf);
    offmask_mfma_kernel<<<dim3(256), dim3(512), 0, stream>>>(
        xhf, offb, modb, owf, offm);
    deform_nhwc_kernel<<<dim3(256), dim3(512), 0, stream>>>(
        xhf, offm, wTb, out);
}

// Round 10
// 65.322 us; speedup vs baseline: 4.8269x; 1.0630x over previous
//
#include <hip/hip_runtime.h>
#include <math.h>

// Modulated deformable conv v2: B=4, C=256, H=W=64, O=256, K=3, PAD=1
// r27: K2 -> LDS-TILE DIRECT-READ conv. Static 3x3 taps => stage the
//      zero-padded 3-row x-neighborhood (3 x 66 x 256 fp16 = 101KB) in LDS
//      once, read MFMA B-frags directly from the tile (octet-XOR swizzle,
//      same bank pattern as the verified cols read). Eliminates per-tap
//      gathers (576KB L1/block), cols staging, and all 18 in-loop barriers.
//      K1 verbatim; K3 = r26 verbatim (44.8us, best measured).

constexpr int Bn = 4;
constexpr int Cn = 256;
constexpr int Hn = 64;
constexpr int Wn = 64;
constexpr int On = 256;
constexpr int PB = Hn * Wn;     // 4096
constexpr int NCH = 27;

typedef __attribute__((ext_vector_type(8))) _Float16 f16x8;  // 4 VGPRs
typedef __attribute__((ext_vector_type(2))) _Float16 f16x2;
typedef __attribute__((ext_vector_type(4))) float f32x4;

union FragU { uint4 u; f16x8 h; };

__device__ inline ushort f2h(float f) {
    _Float16 h = (_Float16)f;
    return __builtin_bit_cast(ushort, h);
}
__device__ inline uint pkh(float a, float b) {
    return __builtin_bit_cast(uint, __builtin_amdgcn_cvt_pkrtz(a, b));
}
__device__ inline f16x2 u2h(uint u) { return __builtin_bit_cast(f16x2, u); }
__device__ inline uint h2u(f16x2 h) { return __builtin_bit_cast(uint, h); }

// ---------------------------------------------------------------- kernel 1
// NCHW fp32 -> NHWC fp16 plane + fp16 weight packs (r24b verbatim).
__global__ __launch_bounds__(256)
void nhwcpack_kernel(const float* __restrict__ x,
                     const float* __restrict__ w,
                     const float* __restrict__ offw,
                     const float* __restrict__ modw,
                     ushort* __restrict__ xhf,
                     ushort* __restrict__ wTb,
                     ushort* __restrict__ owf)
{
    const int bid = blockIdx.x;
    const int b = bid >> 7, seg = bid & 127;
    const int t = threadIdx.x;
    __shared__ float tile[32][257];

    const float* src = x + (size_t)b * Cn * PB + seg * 32;
    #pragma unroll 4
    for (int i = 0; i < 32; ++i) {
        const int idx = i * 256 + t;
        const int c = idx >> 5, p = idx & 31;
        tile[p][c] = src[(size_t)c * PB + p];
    }
    __syncthreads();

    const int pr = t & 127;
    const int r0 = (t >> 7) * 16;
    uint* dH = reinterpret_cast<uint*>(xhf + ((size_t)b * PB + seg * 32) * 256);
    #pragma unroll 4
    for (int i = 0; i < 16; ++i) {
        const int row = r0 + i;
        const float v0 = tile[row][2 * pr];
        const float v1 = tile[row][2 * pr + 1];
        dH[(size_t)row * 128 + pr] = pkh(v0, v1);
    }

    #pragma unroll 1
    for (int u = 0; u < 5; ++u) {
        int unit = (u < 4) ? bid * 4 + u : (bid < 256 ? 2048 + bid : -1);
        if (unit < 0) break;
        const int tap = unit >> 8, c = unit & 255;
        const int o = t;
        wTb[((size_t)(unit >> 3) * 256 + o) * 8 + (c & 7)] =
            f2h(w[((size_t)o * Cn + c) * 9 + tap]);
        if (o < 32) {
            float v = 0.f;
            if (o < 18)      v = offw[((size_t)o * Cn + c) * 9 + tap];
            else if (o < 27) v = modw[((size_t)(o - 18) * Cn + c) * 9 + tap];
            owf[((size_t)(unit >> 3) * 32 + o) * 8 + (c & 7)] = f2h(v);
        }
    }
}

// ---------------------------------------------------------------- kernel 2
// r27: offset/mask conv via LDS x-tile direct read. grid 256 = (b,row)
// XCD-swizzled, 512 threads = 8 waves = 2 out-tiles x 4 pos-tiles.
// Tile: xt[3][66][256] fp16, zero-padded rows/cols, octet-swizzled
// (octet o of column ci stored at slot o ^ (ci&7)). B-frag for lane
// (l15=pos-in-tile, g) at (tap,s) = one b128 read at octet 4s+g of
// column pos+tx, row ty. No cols, no gathers, no in-loop barriers.
__global__ __launch_bounds__(512, 1)
void offmask_tile_kernel(const ushort* __restrict__ xhf,
                         const float* __restrict__ offb,
                         const float* __restrict__ modb,
                         const ushort* __restrict__ owf,
                         float* __restrict__ offm)
{
    const int hw = blockIdx.x;
    const int blk = (hw & 7) * 32 + (hw >> 3);
    const int b = blk >> 6, row = blk & 63;
    const int t = threadIdx.x;
    const int lane = t & 63;
    const int wv  = t >> 6;
    const int l15 = lane & 15;
    const int g   = lane >> 4;
    const int mt  = wv >> 2;
    const int nt  = wv & 3;

    __shared__ ushort xt[3 * 66 * 256];          // 101,376 B
    uint4* lds4 = reinterpret_cast<uint4*>(xt);  // 16B octets

    // ---- stage: 3 rows (zero-padded), 64 real cols + 2 pad cols ----
    {
        const int c  = t >> 3;           // 0..63
        const int og = (t & 7) * 4;      // starting octet 0,4,..,28
        #pragma unroll 1
        for (int r = 0; r < 3; ++r) {
            const int ysrc = row - 1 + r;
            const int ci = c + 1;
            const int base = (r * 66 + ci) * 32;
            if (ysrc >= 0 && ysrc < Hn) {
                const uint4* src = reinterpret_cast<const uint4*>(
                    xhf + ((size_t)(b * PB + ysrc * 64 + c)) * 256);
                #pragma unroll
                for (int j = 0; j < 4; ++j) {
                    const int o = og + j;
                    lds4[base + (o ^ (ci & 7))] = src[o];
                }
            } else {
                const uint4 z = make_uint4(0u, 0u, 0u, 0u);
                #pragma unroll
                for (int j = 0; j < 4; ++j) {
                    const int o = og + j;
                    lds4[base + (o ^ (ci & 7))] = z;
                }
            }
        }
        // pad columns ci=0 and ci=65 (3 rows x 2 cols x 32 octets = 192)
        if (t < 192) {
            const int r = t >> 6, idx = t & 63;
            const int ci = (idx >= 32) ? 65 : 0;
            const int o = idx & 31;
            lds4[(r * 66 + ci) * 32 + (o ^ (ci & 7))] =
                make_uint4(0u, 0u, 0u, 0u);
        }
    }
    __syncthreads();   // the ONLY barrier

    const uint4* owfV = reinterpret_cast<const uint4*>(owf);
    f32x4 acc = (f32x4){0.f, 0.f, 0.f, 0.f};
    const int pos = nt * 16 + l15;               // position in row (0..63)

    #pragma unroll 1
    for (int tap = 0; tap < 9; ++tap) {
        const int ty = tap / 3, tx = tap % 3;
        const int ci = pos + tx;                 // tile column (0..65)
        const int cbase = (ty * 66 + ci) * 32;
        const int cx = ci & 7;

        uint4 aH[8];
        #pragma unroll
        for (int s = 0; s < 8; ++s) {
            const size_t kb = (size_t)((tap * 8 + s) * 4 + g) * 32 + mt * 16 + l15;
            aH[s] = owfV[kb];
        }

        #pragma unroll
        for (int s = 0; s < 8; ++s) {
            FragU aHH, bH;
            aHH.u = aH[s];
            bH.u = lds4[cbase + ((4 * s + g) ^ cx)];
            acc = __builtin_amdgcn_mfma_f32_16x16x32_f16(aHH.h, bH.h, acc, 0, 0, 0);
        }
    }

    #pragma unroll
    for (int j = 0; j < 4; ++j) {
        const int ch = mt * 16 + g * 4 + j;
        if (ch < NCH) {
            float v = acc[j];
            if (ch < 18) v += offb[ch];
            else         v = 2.f / (1.f + expf(-(v + modb[ch - 18])));
            offm[((size_t)(b * NCH + ch)) * PB + row * 64 + pos] = v;
        }
    }
}

// ---------------------------------------------------------------- kernel 3
// r26 verbatim: r24b frame + packed-fp16 combine (44.8us, best measured).
__global__ __launch_bounds__(512, 2)
void deform_nhwc_kernel(const ushort* __restrict__ xhf,
                        const float* __restrict__ offm,
                        const ushort* __restrict__ wTb,
                        float* __restrict__ out)
{
    const int hw = blockIdx.x;
    const int blk = (hw & 7) * 32 + (hw >> 3);   // XCD swizzle (256 = 8*32)
    const int b = blk >> 6, row = blk & 63;
    const int p0 = row * 64;
    const int t = threadIdx.x;
    const int lane = t & 63;
    const int wv  = t >> 6;
    const int l15 = lane & 15;
    const int g   = lane >> 4;

    __shared__ int4  s_off[576];       // [tap][pos 0..63]
    __shared__ uint4 s_wgt[576];       // duplicated-fp16 weight pairs
    __shared__ uint  cols[4][1024];    // [step][pos*16+slot] (16 KB)

    for (int ti = t; ti < 576; ti += 512) {
        const int k = ti >> 6, pos = ti & 63;
        const int p = p0 + pos;
        const float dy = offm[((size_t)(b * NCH + 2 * k)) * PB + p];
        const float dx = offm[((size_t)(b * NCH + 2 * k + 1)) * PB + p];
        const float m  = offm[((size_t)(b * NCH + 18 + k)) * PB + p];
        const int ky = k / 3, kx = k % 3;
        const float py = dy + (float)(ky + row - 1);
        const float px = dx + (float)(kx + pos - 1);
        const float y0f = floorf(py), x0f = floorf(px);
        const float fy = py - y0f, fx = px - x0f;
        const int y0 = (int)y0f, x0i = (int)x0f;
        const int y1 = y0 + 1, x1 = x0i + 1;
        const bool vy0 = (y0 >= 0) && (y0 < Hn);
        const bool vy1 = (y1 >= 0) && (y1 < Hn);
        const bool vx0 = (x0i >= 0) && (x0i < Wn);
        const bool vx1 = (x1 >= 0) && (x1 < Wn);
        const int y0c = min(max(y0, 0), Hn - 1);
        const int y1c = min(max(y1, 0), Hn - 1);
        const int x0c = min(max(x0i, 0), Wn - 1);
        const int x1c = min(max(x1, 0), Wn - 1);
        s_off[ti] = make_int4(y0c * Wn + x0c, y0c * Wn + x1c,
                              y1c * Wn + x0c, y1c * Wn + x1c);
        const float w0 = (vy0 && vx0) ? (1.f - fy) * (1.f - fx) * m : 0.f;
        const float w1 = (vy0 && vx1) ? (1.f - fy) * fx * m : 0.f;
        const float w2 = (vy1 && vx0) ? fy * (1.f - fx) * m : 0.f;
        const float w3 = (vy1 && vx1) ? fy * fx * m : 0.f;
        s_wgt[ti] = make_uint4(pkh(w0, w0), pkh(w1, w1),
                               pkh(w2, w2), pkh(w3, w3));
    }
    __syncthreads();   // tap tables visible before ANY gather

    const ushort* xb = xhf + (size_t)b * PB * 256;
    const int posT = t >> 4;       // 0..31; this thread stages posT and posT+32
    const int chq  = t & 15;
    const uint4* wvp = reinterpret_cast<const uint4*>(wTb);
    const int o0 = wv * 32;

    const int ws0 = posT * 16
        + 4 * ((chq >> 2) ^ (posT & 3) ^ ((posT >> 2) & 3)) + (chq & 3);
    // posT+32: low bits of pos identical -> slot = ws0 + 512

    int ri[4];
    #pragma unroll
    for (int nt = 0; nt < 4; ++nt) {
        const int p = nt * 16 + l15;
        ri[nt] = p * 4 + (g ^ (p & 3) ^ ((p >> 2) & 3));
    }

    f32x4 acc[2][4];
    #pragma unroll
    for (int ot = 0; ot < 2; ++ot)
        #pragma unroll
        for (int nt = 0; nt < 4; ++nt)
            acc[ot][nt] = (f32x4){0.f, 0.f, 0.f, 0.f};

    #pragma unroll 1
    for (int cch = 0; cch < 18; ++cch) {
        const int tap = cch >> 1, cc0 = (cch & 1) * 128;
        const int4  offA = s_off[tap * 64 + posT];
        const uint4 wgtA = s_wgt[tap * 64 + posT];
        const int4  offB = s_off[tap * 64 + posT + 32];
        const uint4 wgtB = s_wgt[tap * 64 + posT + 32];
        const ushort* xc = xb + cc0 + 2 * chq;

        // ---- issue 32 fp16 gathers (2 pos x 4 corners x 4 steps) + 8 A-loads
        uint qa[4], qb[4], qc[4], qd[4], ra[4], rb[4], rc[4], rd[4];
        #pragma unroll
        for (int s = 0; s < 4; ++s) {
            const int so = s * 32;
            qa[s] = *reinterpret_cast<const uint*>(xc + (size_t)offA.x * 256 + so);
            qb[s] = *reinterpret_cast<const uint*>(xc + (size_t)offA.y * 256 + so);
            qc[s] = *reinterpret_cast<const uint*>(xc + (size_t)offA.z * 256 + so);
            qd[s] = *reinterpret_cast<const uint*>(xc + (size_t)offA.w * 256 + so);
            ra[s] = *reinterpret_cast<const uint*>(xc + (size_t)offB.x * 256 + so);
            rb[s] = *reinterpret_cast<const uint*>(xc + (size_t)offB.y * 256 + so);
            rc[s] = *reinterpret_cast<const uint*>(xc + (size_t)offB.z * 256 + so);
            rd[s] = *reinterpret_cast<const uint*>(xc + (size_t)offB.w * 256 + so);
        }
        uint4 apre[4][2];
        #pragma unroll
        for (int s = 0; s < 4; ++s) {
            const int kb = (cch * 4 + s) * 4 + g;
            apre[s][0] = wvp[(size_t)kb * 256 + o0 + l15];
            apre[s][1] = wvp[(size_t)kb * 256 + o0 + 16 + l15];
        }

        __syncthreads();   // prior chunk's MFMA reads complete before overwrite

        // ---- packed fp16 bilinear combine: 4 pk ops per pair ----
        #pragma unroll
        for (int s = 0; s < 4; ++s) {
            f16x2 v = u2h(qa[s]) * u2h(wgtA.x);
            v += u2h(qb[s]) * u2h(wgtA.y);
            v += u2h(qc[s]) * u2h(wgtA.z);
            v += u2h(qd[s]) * u2h(wgtA.w);
            cols[s][ws0] = h2u(v);
            f16x2 u = u2h(ra[s]) * u2h(wgtB.x);
            u += u2h(rb[s]) * u2h(wgtB.y);
            u += u2h(rc[s]) * u2h(wgtB.z);
            u += u2h(rd[s]) * u2h(wgtB.w);
            cols[s][ws0 + 512] = h2u(u);
        }
        __syncthreads();   // writes visible before MFMA reads

        #pragma unroll
        for (int s = 0; s < 4; ++s) {
            FragU a0, a1, bf[4];
            a0.u = apre[s][0]; a1.u = apre[s][1];
            #pragma unroll
            for (int nt = 0; nt < 4; ++nt)
                bf[nt].u = reinterpret_cast<const uint4*>(cols[s])[ri[nt]];
            #pragma unroll
            for (int nt = 0; nt < 4; ++nt) {
                acc[0][nt] = __builtin_amdgcn_mfma_f32_16x16x32_f16(
                    a0.h, bf[nt].h, acc[0][nt], 0, 0, 0);
                acc[1][nt] = __builtin_amdgcn_mfma_f32_16x16x32_f16(
                    a1.h, bf[nt].h, acc[1][nt], 0, 0, 0);
            }
        }
    }

    float* ob = out + (size_t)b * On * PB;
    #pragma unroll
    for (int ot = 0; ot < 2; ++ot)
        #pragma unroll
        for (int nt = 0; nt < 4; ++nt)
            #pragma unroll
            for (int j = 0; j < 4; ++j)
                ob[((size_t)(o0 + ot * 16 + g * 4 + j)) * PB
                   + p0 + nt * 16 + l15] = acc[ot][nt][j];
}

// ---------------------------------------------------------------- launch
extern "C" void kernel_launch(void* const* d_in, const int* in_sizes, int n_in,
                              void* d_out, int out_size, void* d_ws, size_t ws_size,
                              hipStream_t stream)
{
    const float* x    = (const float*)d_in[0];
    const float* offw = (const float*)d_in[1];
    const float* offb = (const float*)d_in[2];
    const float* modw = (const float*)d_in[3];
    const float* modb = (const float*)d_in[4];
    const float* wgt  = (const float*)d_in[5];
    float* out = (float*)d_out;

    char* ws = (char*)d_ws;
    float*  offm = (float*)ws;                   // 1,769,472 B
    ushort* wTb  = (ushort*)(ws + 1769472);      // 1,179,648 B
    ushort* owf  = (ushort*)(ws + 2949120);      // 147,456 B
    ushort* xhf  = (ushort*)(ws + 3244032);      // 8,388,608 B (fp16 NHWC)

    nhwcpack_kernel<<<dim3(512), dim3(256), 0, stream>>>(
        x, wgt, offw, modw, xhf, wTb, owf);
    offmask_tile_kernel<<<dim3(256), dim3(512), 0, stream>>>(
        xhf, offb, modb, owf, offm);
    deform_nhwc_kernel<<<dim3(256), dim3(512), 0, stream>>>(
        xhf, offm, wTb, out);
}

// Round 11
// 61.984 us; speedup vs baseline: 5.0868x; 1.0539x over previous
//
#include <hip/hip_runtime.h>
#include <math.h>

// Modulated deformable conv v2: B=4, C=256, H=W=64, O=256, K=3, PAD=1
// r28: K3 FULL SOFTWARE PIPELINE (fixing r19's defect): BOTH gathers and
//      A-fragment loads are double-buffered one chunk ahead, issued
//      A-before-gathers so the combine's wait on the OLDEST gather set
//      leaves all 40 next-chunk loads in flight (counted vmcnt, never 0).
//      The MFMA phase consumes A from registers -> zero VMEM waits there.
//      dbuf cols + lgkmcnt-only raw barriers (r19-verified sync pattern).
//      K1 verbatim; K2 = r27 LDS-tile direct-read (proven).

constexpr int Bn = 4;
constexpr int Cn = 256;
constexpr int Hn = 64;
constexpr int Wn = 64;
constexpr int On = 256;
constexpr int PB = Hn * Wn;     // 4096
constexpr int NCH = 27;

typedef __attribute__((ext_vector_type(8))) _Float16 f16x8;  // 4 VGPRs
typedef __attribute__((ext_vector_type(2))) _Float16 f16x2;
typedef __attribute__((ext_vector_type(4))) float f32x4;

union FragU { uint4 u; f16x8 h; };

__device__ inline ushort f2h(float f) {
    _Float16 h = (_Float16)f;
    return __builtin_bit_cast(ushort, h);
}
__device__ inline uint pkh(float a, float b) {
    return __builtin_bit_cast(uint, __builtin_amdgcn_cvt_pkrtz(a, b));
}
__device__ inline f16x2 u2h(uint u) { return __builtin_bit_cast(f16x2, u); }
__device__ inline uint h2u(f16x2 h) { return __builtin_bit_cast(uint, h); }

// ---------------------------------------------------------------- kernel 1
// NCHW fp32 -> NHWC fp16 plane + fp16 weight packs (r24b verbatim).
__global__ __launch_bounds__(256)
void nhwcpack_kernel(const float* __restrict__ x,
                     const float* __restrict__ w,
                     const float* __restrict__ offw,
                     const float* __restrict__ modw,
                     ushort* __restrict__ xhf,
                     ushort* __restrict__ wTb,
                     ushort* __restrict__ owf)
{
    const int bid = blockIdx.x;
    const int b = bid >> 7, seg = bid & 127;
    const int t = threadIdx.x;
    __shared__ float tile[32][257];

    const float* src = x + (size_t)b * Cn * PB + seg * 32;
    #pragma unroll 4
    for (int i = 0; i < 32; ++i) {
        const int idx = i * 256 + t;
        const int c = idx >> 5, p = idx & 31;
        tile[p][c] = src[(size_t)c * PB + p];
    }
    __syncthreads();

    const int pr = t & 127;
    const int r0 = (t >> 7) * 16;
    uint* dH = reinterpret_cast<uint*>(xhf + ((size_t)b * PB + seg * 32) * 256);
    #pragma unroll 4
    for (int i = 0; i < 16; ++i) {
        const int row = r0 + i;
        const float v0 = tile[row][2 * pr];
        const float v1 = tile[row][2 * pr + 1];
        dH[(size_t)row * 128 + pr] = pkh(v0, v1);
    }

    #pragma unroll 1
    for (int u = 0; u < 5; ++u) {
        int unit = (u < 4) ? bid * 4 + u : (bid < 256 ? 2048 + bid : -1);
        if (unit < 0) break;
        const int tap = unit >> 8, c = unit & 255;
        const int o = t;
        wTb[((size_t)(unit >> 3) * 256 + o) * 8 + (c & 7)] =
            f2h(w[((size_t)o * Cn + c) * 9 + tap]);
        if (o < 32) {
            float v = 0.f;
            if (o < 18)      v = offw[((size_t)o * Cn + c) * 9 + tap];
            else if (o < 27) v = modw[((size_t)(o - 18) * Cn + c) * 9 + tap];
            owf[((size_t)(unit >> 3) * 32 + o) * 8 + (c & 7)] = f2h(v);
        }
    }
}

// ---------------------------------------------------------------- kernel 2
// r27: offset/mask conv via LDS x-tile direct read (verbatim).
__global__ __launch_bounds__(512, 1)
void offmask_tile_kernel(const ushort* __restrict__ xhf,
                         const float* __restrict__ offb,
                         const float* __restrict__ modb,
                         const ushort* __restrict__ owf,
                         float* __restrict__ offm)
{
    const int hw = blockIdx.x;
    const int blk = (hw & 7) * 32 + (hw >> 3);
    const int b = blk >> 6, row = blk & 63;
    const int t = threadIdx.x;
    const int lane = t & 63;
    const int wv  = t >> 6;
    const int l15 = lane & 15;
    const int g   = lane >> 4;
    const int mt  = wv >> 2;
    const int nt  = wv & 3;

    __shared__ ushort xt[3 * 66 * 256];          // 101,376 B
    uint4* lds4 = reinterpret_cast<uint4*>(xt);  // 16B octets

    {
        const int c  = t >> 3;           // 0..63
        const int og = (t & 7) * 4;      // starting octet 0,4,..,28
        #pragma unroll 1
        for (int r = 0; r < 3; ++r) {
            const int ysrc = row - 1 + r;
            const int ci = c + 1;
            const int base = (r * 66 + ci) * 32;
            if (ysrc >= 0 && ysrc < Hn) {
                const uint4* src = reinterpret_cast<const uint4*>(
                    xhf + ((size_t)(b * PB + ysrc * 64 + c)) * 256);
                #pragma unroll
                for (int j = 0; j < 4; ++j) {
                    const int o = og + j;
                    lds4[base + (o ^ (ci & 7))] = src[o];
                }
            } else {
                const uint4 z = make_uint4(0u, 0u, 0u, 0u);
                #pragma unroll
                for (int j = 0; j < 4; ++j) {
                    const int o = og + j;
                    lds4[base + (o ^ (ci & 7))] = z;
                }
            }
        }
        if (t < 192) {
            const int r = t >> 6, idx = t & 63;
            const int ci = (idx >= 32) ? 65 : 0;
            const int o = idx & 31;
            lds4[(r * 66 + ci) * 32 + (o ^ (ci & 7))] =
                make_uint4(0u, 0u, 0u, 0u);
        }
    }
    __syncthreads();   // the ONLY barrier

    const uint4* owfV = reinterpret_cast<const uint4*>(owf);
    f32x4 acc = (f32x4){0.f, 0.f, 0.f, 0.f};
    const int pos = nt * 16 + l15;

    #pragma unroll 1
    for (int tap = 0; tap < 9; ++tap) {
        const int ty = tap / 3, tx = tap % 3;
        const int ci = pos + tx;
        const int cbase = (ty * 66 + ci) * 32;
        const int cx = ci & 7;

        uint4 aH[8];
        #pragma unroll
        for (int s = 0; s < 8; ++s) {
            const size_t kb = (size_t)((tap * 8 + s) * 4 + g) * 32 + mt * 16 + l15;
            aH[s] = owfV[kb];
        }

        #pragma unroll
        for (int s = 0; s < 8; ++s) {
            FragU aHH, bH;
            aHH.u = aH[s];
            bH.u = lds4[cbase + ((4 * s + g) ^ cx)];
            acc = __builtin_amdgcn_mfma_f32_16x16x32_f16(aHH.h, bH.h, acc, 0, 0, 0);
        }
    }

    #pragma unroll
    for (int j = 0; j < 4; ++j) {
        const int ch = mt * 16 + g * 4 + j;
        if (ch < NCH) {
            float v = acc[j];
            if (ch < 18) v += offb[ch];
            else         v = 2.f / (1.f + expf(-(v + modb[ch - 18])));
            offm[((size_t)(b * NCH + ch)) * PB + row * 64 + pos] = v;
        }
    }
}

// ---------------------------------------------------------------- kernel 3
// r28: r26 frame with FULL dbuf pipeline (gathers AND A prefetched).
__global__ __launch_bounds__(512, 1)
void deform_nhwc_kernel(const ushort* __restrict__ xhf,
                        const float* __restrict__ offm,
                        const ushort* __restrict__ wTb,
                        float* __restrict__ out)
{
    const int hw = blockIdx.x;
    const int blk = (hw & 7) * 32 + (hw >> 3);   // XCD swizzle (256 = 8*32)
    const int b = blk >> 6, row = blk & 63;
    const int p0 = row * 64;
    const int t = threadIdx.x;
    const int lane = t & 63;
    const int wv  = t >> 6;
    const int l15 = lane & 15;
    const int g   = lane >> 4;

    __shared__ int4  s_off[576];       // [tap][pos 0..63]
    __shared__ uint4 s_wgt[576];       // duplicated-fp16 weight pairs
    __shared__ uint  cols[2][4][1024]; // double-buffered (32 KB)

    for (int ti = t; ti < 576; ti += 512) {
        const int k = ti >> 6, pos = ti & 63;
        const int p = p0 + pos;
        const float dy = offm[((size_t)(b * NCH + 2 * k)) * PB + p];
        const float dx = offm[((size_t)(b * NCH + 2 * k + 1)) * PB + p];
        const float m  = offm[((size_t)(b * NCH + 18 + k)) * PB + p];
        const int ky = k / 3, kx = k % 3;
        const float py = dy + (float)(ky + row - 1);
        const float px = dx + (float)(kx + pos - 1);
        const float y0f = floorf(py), x0f = floorf(px);
        const float fy = py - y0f, fx = px - x0f;
        const int y0 = (int)y0f, x0i = (int)x0f;
        const int y1 = y0 + 1, x1 = x0i + 1;
        const bool vy0 = (y0 >= 0) && (y0 < Hn);
        const bool vy1 = (y1 >= 0) && (y1 < Hn);
        const bool vx0 = (x0i >= 0) && (x0i < Wn);
        const bool vx1 = (x1 >= 0) && (x1 < Wn);
        const int y0c = min(max(y0, 0), Hn - 1);
        const int y1c = min(max(y1, 0), Hn - 1);
        const int x0c = min(max(x0i, 0), Wn - 1);
        const int x1c = min(max(x1, 0), Wn - 1);
        s_off[ti] = make_int4(y0c * Wn + x0c, y0c * Wn + x1c,
                              y1c * Wn + x0c, y1c * Wn + x1c);
        const float w0 = (vy0 && vx0) ? (1.f - fy) * (1.f - fx) * m : 0.f;
        const float w1 = (vy0 && vx1) ? (1.f - fy) * fx * m : 0.f;
        const float w2 = (vy1 && vx0) ? fy * (1.f - fx) * m : 0.f;
        const float w3 = (vy1 && vx1) ? fy * fx * m : 0.f;
        s_wgt[ti] = make_uint4(pkh(w0, w0), pkh(w1, w1),
                               pkh(w2, w2), pkh(w3, w3));
    }
    __syncthreads();   // tap tables visible before ANY gather

    const ushort* xb = xhf + (size_t)b * PB * 256;
    const int posT = t >> 4;       // 0..31; stages posT and posT+32
    const int chq  = t & 15;
    const uint4* wvp = reinterpret_cast<const uint4*>(wTb);
    const int o0 = wv * 32;

    const int ws0 = posT * 16
        + 4 * ((chq >> 2) ^ (posT & 3) ^ ((posT >> 2) & 3)) + (chq & 3);

    int ri[4];
    #pragma unroll
    for (int nt = 0; nt < 4; ++nt) {
        const int p = nt * 16 + l15;
        ri[nt] = p * 4 + (g ^ (p & 3) ^ ((p >> 2) & 3));
    }

    f32x4 acc[2][4];
    #pragma unroll
    for (int ot = 0; ot < 2; ++ot)
        #pragma unroll
        for (int nt = 0; nt < 4; ++nt)
            acc[ot][nt] = (f32x4){0.f, 0.f, 0.f, 0.f};

    // A-loads FIRST, then gathers: waiting for the gather set implies the
    // matching A set is complete (vmcnt is ordered).
    auto LOADA = [&](int cch, uint4 (&ap)[4][2]) {
        #pragma unroll
        for (int s = 0; s < 4; ++s) {
            const int kb = (cch * 4 + s) * 4 + g;
            ap[s][0] = wvp[(size_t)kb * 256 + o0 + l15];
            ap[s][1] = wvp[(size_t)kb * 256 + o0 + 16 + l15];
        }
    };

    auto ISSUE = [&](int cch, uint (&gg)[32]) {
        const int tap = cch >> 1, cc0 = (cch & 1) * 128;
        const int4 oA = s_off[tap * 64 + posT];
        const int4 oB = s_off[tap * 64 + posT + 32];
        const ushort* xc = xb + cc0 + 2 * chq;
        #pragma unroll
        for (int s = 0; s < 4; ++s) {
            const int so = s * 32;
            gg[s * 8 + 0] = *reinterpret_cast<const uint*>(xc + (size_t)oA.x * 256 + so);
            gg[s * 8 + 1] = *reinterpret_cast<const uint*>(xc + (size_t)oA.y * 256 + so);
            gg[s * 8 + 2] = *reinterpret_cast<const uint*>(xc + (size_t)oA.z * 256 + so);
            gg[s * 8 + 3] = *reinterpret_cast<const uint*>(xc + (size_t)oA.w * 256 + so);
            gg[s * 8 + 4] = *reinterpret_cast<const uint*>(xc + (size_t)oB.x * 256 + so);
            gg[s * 8 + 5] = *reinterpret_cast<const uint*>(xc + (size_t)oB.y * 256 + so);
            gg[s * 8 + 6] = *reinterpret_cast<const uint*>(xc + (size_t)oB.z * 256 + so);
            gg[s * 8 + 7] = *reinterpret_cast<const uint*>(xc + (size_t)oB.w * 256 + so);
        }
    };

    auto COMBINE = [&](int cch, const uint (&gg)[32], uint* cbuf) {
        const int tap = cch >> 1;
        const uint4 wgtA = s_wgt[tap * 64 + posT];
        const uint4 wgtB = s_wgt[tap * 64 + posT + 32];
        #pragma unroll
        for (int s = 0; s < 4; ++s) {
            f16x2 v = u2h(gg[s * 8 + 0]) * u2h(wgtA.x);
            v += u2h(gg[s * 8 + 1]) * u2h(wgtA.y);
            v += u2h(gg[s * 8 + 2]) * u2h(wgtA.z);
            v += u2h(gg[s * 8 + 3]) * u2h(wgtA.w);
            cbuf[s * 1024 + ws0] = h2u(v);
            f16x2 u = u2h(gg[s * 8 + 4]) * u2h(wgtB.x);
            u += u2h(gg[s * 8 + 5]) * u2h(wgtB.y);
            u += u2h(gg[s * 8 + 6]) * u2h(wgtB.z);
            u += u2h(gg[s * 8 + 7]) * u2h(wgtB.w);
            cbuf[s * 1024 + ws0 + 512] = h2u(u);
        }
    };

    auto MFMAS = [&](const uint* cbuf, const uint4 (&ap)[4][2]) {
        #pragma unroll
        for (int s = 0; s < 4; ++s) {
            FragU a0, a1, bf[4];
            a0.u = ap[s][0]; a1.u = ap[s][1];
            #pragma unroll
            for (int nt = 0; nt < 4; ++nt)
                bf[nt].u = reinterpret_cast<const uint4*>(cbuf + s * 1024)[ri[nt]];
            #pragma unroll
            for (int nt = 0; nt < 4; ++nt) {
                acc[0][nt] = __builtin_amdgcn_mfma_f32_16x16x32_f16(
                    a0.h, bf[nt].h, acc[0][nt], 0, 0, 0);
                acc[1][nt] = __builtin_amdgcn_mfma_f32_16x16x32_f16(
                    a1.h, bf[nt].h, acc[1][nt], 0, 0, 0);
            }
        }
    };

    uint  gA[32], gB[32];
    uint4 aA[4][2], aB[4][2];

    LOADA(0, aA);
    ISSUE(0, gA);
    #pragma unroll 1
    for (int jj = 0; jj < 9; ++jj) {
        // even phase: cch = 2*jj (data in gA/aA, buffer 0)
        LOADA(2 * jj + 1, aB);
        ISSUE(2 * jj + 1, gB);
        COMBINE(2 * jj, gA, &cols[0][0][0]);     // waits OLDEST gathers only
        asm volatile("s_waitcnt lgkmcnt(0)" ::: "memory");
        __builtin_amdgcn_s_barrier();
        asm volatile("" ::: "memory");
        MFMAS(&cols[0][0][0], aA);               // A already in registers

        // odd phase: cch = 2*jj+1 (data in gB/aB, buffer 1)
        if (jj < 8) {
            LOADA(2 * jj + 2, aA);
            ISSUE(2 * jj + 2, gA);
        }
        COMBINE(2 * jj + 1, gB, &cols[1][0][0]);
        asm volatile("s_waitcnt lgkmcnt(0)" ::: "memory");
        __builtin_amdgcn_s_barrier();
        asm volatile("" ::: "memory");
        MFMAS(&cols[1][0][0], aB);
    }

    float* ob = out + (size_t)b * On * PB;
    #pragma unroll
    for (int ot = 0; ot < 2; ++ot)
        #pragma unroll
        for (int nt = 0; nt < 4; ++nt)
            #pragma unroll
            for (int j = 0; j < 4; ++j)
                ob[((size_t)(o0 + ot * 16 + g * 4 + j)) * PB
                   + p0 + nt * 16 + l15] = acc[ot][nt][j];
}

// ---------------------------------------------------------------- launch
extern "C" void kernel_launch(void* const* d_in, const int* in_sizes, int n_in,
                              void* d_out, int out_size, void* d_ws, size_t ws_size,
                              hipStream_t stream)
{
    const float* x    = (const float*)d_in[0];
    const float* offw = (const float*)d_in[1];
    const float* offb = (const float*)d_in[2];
    const float* modw = (const float*)d_in[3];
    const float* modb = (const float*)d_in[4];
    const float* wgt  = (const float*)d_in[5];
    float* out = (float*)d_out;

    char* ws = (char*)d_ws;
    float*  offm = (float*)ws;                   // 1,769,472 B
    ushort* wTb  = (ushort*)(ws + 1769472);      // 1,179,648 B
    ushort* owf  = (ushort*)(ws + 2949120);      // 147,456 B
    ushort* xhf  = (ushort*)(ws + 3244032);      // 8,388,608 B (fp16 NHWC)

    nhwcpack_kernel<<<dim3(512), dim3(256), 0, stream>>>(
        x, wgt, offw, modw, xhf, wTb, owf);
    offmask_tile_kernel<<<dim3(256), dim3(512), 0, stream>>>(
        xhf, offb, modb, owf, offm);
    deform_nhwc_kernel<<<dim3(256), dim3(512), 0, stream>>>(
        xhf, offm, wTb, out);
}

// Round 12
// 57.026 us; speedup vs baseline: 5.5291x; 1.0869x over previous
//
#include <hip/hip_runtime.h>
#include <math.h>

// Modulated deformable conv v2: B=4, C=256, H=W=64, O=256, K=3, PAD=1
// r29: K3 -> PRODUCER/CONSUMER WAVE SPECIALIZATION (AITER pattern).
//   4 producer waves: gather 4 corners (dwordx4) for 4 (pos,octet) units,
//     packed-fp16 blend, write swizzled uint4 slots into a 2-deep cols ring.
//   4 consumer waves: A-loads (dbuf, own vmcnt stream), cols b128 reads,
//     64out x 64pos accumulator, setprio(1) around MFMA cluster.
//   Per-wave vmcnt independence + producer/consumer SIMD pairing (m114)
//   turns the phase cost from sum-of-pipes into max-of-pipes.
//   Sync: 18 block-wide s_barriers, 2-deep ring (write c+1 || read c).
//   K1 verbatim; K2 = r27 LDS-tile direct-read (proven).

constexpr int Bn = 4;
constexpr int Cn = 256;
constexpr int Hn = 64;
constexpr int Wn = 64;
constexpr int On = 256;
constexpr int PB = Hn * Wn;     // 4096
constexpr int NCH = 27;

typedef __attribute__((ext_vector_type(8))) _Float16 f16x8;  // 4 VGPRs
typedef __attribute__((ext_vector_type(2))) _Float16 f16x2;
typedef __attribute__((ext_vector_type(4))) float f32x4;
typedef __attribute__((ext_vector_type(4))) uint  uint4v;

union FragU { uint4 u; f16x8 h; };

__device__ inline ushort f2h(float f) {
    _Float16 h = (_Float16)f;
    return __builtin_bit_cast(ushort, h);
}
__device__ inline uint pkh(float a, float b) {
    return __builtin_bit_cast(uint, __builtin_amdgcn_cvt_pkrtz(a, b));
}
__device__ inline f16x2 u2h(uint u) { return __builtin_bit_cast(f16x2, u); }
__device__ inline uint h2u(f16x2 h) { return __builtin_bit_cast(uint, h); }

// ---------------------------------------------------------------- kernel 1
// NCHW fp32 -> NHWC fp16 plane + fp16 weight packs (r24b verbatim).
__global__ __launch_bounds__(256)
void nhwcpack_kernel(const float* __restrict__ x,
                     const float* __restrict__ w,
                     const float* __restrict__ offw,
                     const float* __restrict__ modw,
                     ushort* __restrict__ xhf,
                     ushort* __restrict__ wTb,
                     ushort* __restrict__ owf)
{
    const int bid = blockIdx.x;
    const int b = bid >> 7, seg = bid & 127;
    const int t = threadIdx.x;
    __shared__ float tile[32][257];

    const float* src = x + (size_t)b * Cn * PB + seg * 32;
    #pragma unroll 4
    for (int i = 0; i < 32; ++i) {
        const int idx = i * 256 + t;
        const int c = idx >> 5, p = idx & 31;
        tile[p][c] = src[(size_t)c * PB + p];
    }
    __syncthreads();

    const int pr = t & 127;
    const int r0 = (t >> 7) * 16;
    uint* dH = reinterpret_cast<uint*>(xhf + ((size_t)b * PB + seg * 32) * 256);
    #pragma unroll 4
    for (int i = 0; i < 16; ++i) {
        const int row = r0 + i;
        const float v0 = tile[row][2 * pr];
        const float v1 = tile[row][2 * pr + 1];
        dH[(size_t)row * 128 + pr] = pkh(v0, v1);
    }

    #pragma unroll 1
    for (int u = 0; u < 5; ++u) {
        int unit = (u < 4) ? bid * 4 + u : (bid < 256 ? 2048 + bid : -1);
        if (unit < 0) break;
        const int tap = unit >> 8, c = unit & 255;
        const int o = t;
        wTb[((size_t)(unit >> 3) * 256 + o) * 8 + (c & 7)] =
            f2h(w[((size_t)o * Cn + c) * 9 + tap]);
        if (o < 32) {
            float v = 0.f;
            if (o < 18)      v = offw[((size_t)o * Cn + c) * 9 + tap];
            else if (o < 27) v = modw[((size_t)(o - 18) * Cn + c) * 9 + tap];
            owf[((size_t)(unit >> 3) * 32 + o) * 8 + (c & 7)] = f2h(v);
        }
    }
}

// ---------------------------------------------------------------- kernel 2
// r27: offset/mask conv via LDS x-tile direct read (verbatim).
__global__ __launch_bounds__(512, 1)
void offmask_tile_kernel(const ushort* __restrict__ xhf,
                         const float* __restrict__ offb,
                         const float* __restrict__ modb,
                         const ushort* __restrict__ owf,
                         float* __restrict__ offm)
{
    const int hw = blockIdx.x;
    const int blk = (hw & 7) * 32 + (hw >> 3);
    const int b = blk >> 6, row = blk & 63;
    const int t = threadIdx.x;
    const int lane = t & 63;
    const int wv  = t >> 6;
    const int l15 = lane & 15;
    const int g   = lane >> 4;
    const int mt  = wv >> 2;
    const int nt  = wv & 3;

    __shared__ ushort xt[3 * 66 * 256];          // 101,376 B
    uint4* lds4 = reinterpret_cast<uint4*>(xt);  // 16B octets

    {
        const int c  = t >> 3;           // 0..63
        const int og = (t & 7) * 4;      // starting octet 0,4,..,28
        #pragma unroll 1
        for (int r = 0; r < 3; ++r) {
            const int ysrc = row - 1 + r;
            const int ci = c + 1;
            const int base = (r * 66 + ci) * 32;
            if (ysrc >= 0 && ysrc < Hn) {
                const uint4* src = reinterpret_cast<const uint4*>(
                    xhf + ((size_t)(b * PB + ysrc * 64 + c)) * 256);
                #pragma unroll
                for (int j = 0; j < 4; ++j) {
                    const int o = og + j;
                    lds4[base + (o ^ (ci & 7))] = src[o];
                }
            } else {
                const uint4 z = make_uint4(0u, 0u, 0u, 0u);
                #pragma unroll
                for (int j = 0; j < 4; ++j) {
                    const int o = og + j;
                    lds4[base + (o ^ (ci & 7))] = z;
                }
            }
        }
        if (t < 192) {
            const int r = t >> 6, idx = t & 63;
            const int ci = (idx >= 32) ? 65 : 0;
            const int o = idx & 31;
            lds4[(r * 66 + ci) * 32 + (o ^ (ci & 7))] =
                make_uint4(0u, 0u, 0u, 0u);
        }
    }
    __syncthreads();   // the ONLY barrier

    const uint4* owfV = reinterpret_cast<const uint4*>(owf);
    f32x4 acc = (f32x4){0.f, 0.f, 0.f, 0.f};
    const int pos = nt * 16 + l15;

    #pragma unroll 1
    for (int tap = 0; tap < 9; ++tap) {
        const int ty = tap / 3, tx = tap % 3;
        const int ci = pos + tx;
        const int cbase = (ty * 66 + ci) * 32;
        const int cx = ci & 7;

        uint4 aH[8];
        #pragma unroll
        for (int s = 0; s < 8; ++s) {
            const size_t kb = (size_t)((tap * 8 + s) * 4 + g) * 32 + mt * 16 + l15;
            aH[s] = owfV[kb];
        }

        #pragma unroll
        for (int s = 0; s < 8; ++s) {
            FragU aHH, bH;
            aHH.u = aH[s];
            bH.u = lds4[cbase + ((4 * s + g) ^ cx)];
            acc = __builtin_amdgcn_mfma_f32_16x16x32_f16(aHH.h, bH.h, acc, 0, 0, 0);
        }
    }

    #pragma unroll
    for (int j = 0; j < 4; ++j) {
        const int ch = mt * 16 + g * 4 + j;
        if (ch < NCH) {
            float v = acc[j];
            if (ch < 18) v += offb[ch];
            else         v = 2.f / (1.f + expf(-(v + modb[ch - 18])));
            offm[((size_t)(b * NCH + ch)) * PB + row * 64 + pos] = v;
        }
    }
}

// ---------------------------------------------------------------- kernel 3
// r29: producer/consumer wave-specialized deform conv.
__global__ __launch_bounds__(512, 2)
void deform_ws_kernel(const ushort* __restrict__ xhf,
                      const float* __restrict__ offm,
                      const ushort* __restrict__ wTb,
                      float* __restrict__ out)
{
    const int hw = blockIdx.x;
    const int blk = (hw & 7) * 32 + (hw >> 3);   // XCD swizzle (256 = 8*32)
    const int b = blk >> 6, row = blk & 63;
    const int p0 = row * 64;
    const int t = threadIdx.x;
    const int lane = t & 63;
    const int wv  = t >> 6;
    const int l15 = lane & 15;
    const int g   = lane >> 4;

    __shared__ int4  s_off[576];       // [tap][pos 0..63]
    __shared__ uint4 s_wgt[576];       // duplicated-fp16 weight pairs
    __shared__ uint  cols[2][4][1024]; // 2-deep ring (32 KB)

    for (int ti = t; ti < 576; ti += 512) {
        const int k = ti >> 6, pos = ti & 63;
        const int p = p0 + pos;
        const float dy = offm[((size_t)(b * NCH + 2 * k)) * PB + p];
        const float dx = offm[((size_t)(b * NCH + 2 * k + 1)) * PB + p];
        const float m  = offm[((size_t)(b * NCH + 18 + k)) * PB + p];
        const int ky = k / 3, kx = k % 3;
        const float py = dy + (float)(ky + row - 1);
        const float px = dx + (float)(kx + pos - 1);
        const float y0f = floorf(py), x0f = floorf(px);
        const float fy = py - y0f, fx = px - x0f;
        const int y0 = (int)y0f, x0i = (int)x0f;
        const int y1 = y0 + 1, x1 = x0i + 1;
        const bool vy0 = (y0 >= 0) && (y0 < Hn);
        const bool vy1 = (y1 >= 0) && (y1 < Hn);
        const bool vx0 = (x0i >= 0) && (x0i < Wn);
        const bool vx1 = (x1 >= 0) && (x1 < Wn);
        const int y0c = min(max(y0, 0), Hn - 1);
        const int y1c = min(max(y1, 0), Hn - 1);
        const int x0c = min(max(x0i, 0), Wn - 1);
        const int x1c = min(max(x1, 0), Wn - 1);
        s_off[ti] = make_int4(y0c * Wn + x0c, y0c * Wn + x1c,
                              y1c * Wn + x0c, y1c * Wn + x1c);
        const float w0 = (vy0 && vx0) ? (1.f - fy) * (1.f - fx) * m : 0.f;
        const float w1 = (vy0 && vx1) ? (1.f - fy) * fx * m : 0.f;
        const float w2 = (vy1 && vx0) ? fy * (1.f - fx) * m : 0.f;
        const float w3 = (vy1 && vx1) ? fy * fx * m : 0.f;
        s_wgt[ti] = make_uint4(pkh(w0, w0), pkh(w1, w1),
                               pkh(w2, w2), pkh(w3, w3));
    }
    __syncthreads();   // tap tables visible to all waves

    const ushort* xb = xhf + (size_t)b * PB * 256;

    if (wv < 4) {
        // ===================== PRODUCER (waves 0-3) =====================
        const int chq  = t & 15;          // channel octet
        const int posT = t >> 4;          // 0..15 (wave = 4 posT x 16 chq)
        const int sIdx = chq >> 2;        // cols K-step plane
        const int grp  = (chq & 3) ^ (posT & 3) ^ ((posT >> 2) & 3);
        const int w4a  = posT * 4 + grp;  // slots for pos posT+16u: +64u
        const ushort* xq = xb + 8 * chq;

        auto PISSUE = [&](int cch, uint4v (&gg)[4][4]) {
            const int tap = cch >> 1;
            const ushort* xcc = xq + (cch & 1) * 128;
            #pragma unroll
            for (int u = 0; u < 4; ++u) {
                const int4 o = s_off[tap * 64 + posT + u * 16];
                gg[u][0] = *reinterpret_cast<const uint4v*>(xcc + (size_t)o.x * 256);
                gg[u][1] = *reinterpret_cast<const uint4v*>(xcc + (size_t)o.y * 256);
                gg[u][2] = *reinterpret_cast<const uint4v*>(xcc + (size_t)o.z * 256);
                gg[u][3] = *reinterpret_cast<const uint4v*>(xcc + (size_t)o.w * 256);
            }
        };

        auto PCOMBINE = [&](int cch, const uint4v (&gg)[4][4], uint* cbuf) {
            const int tap = cch >> 1;
            uint4v* dst = reinterpret_cast<uint4v*>(cbuf + sIdx * 1024);
            #pragma unroll
            for (int u = 0; u < 4; ++u) {
                const uint4 wq = s_wgt[tap * 64 + posT + u * 16];
                uint pr[4];
                #pragma unroll
                for (int j = 0; j < 4; ++j) {
                    f16x2 v = u2h(gg[u][0][j]) * u2h(wq.x);
                    v += u2h(gg[u][1][j]) * u2h(wq.y);
                    v += u2h(gg[u][2][j]) * u2h(wq.z);
                    v += u2h(gg[u][3][j]) * u2h(wq.w);
                    pr[j] = h2u(v);
                }
                dst[w4a + u * 64] = (uint4v){pr[0], pr[1], pr[2], pr[3]};
            }
        };

        uint4v gA[4][4], gB[4][4];
        PISSUE(0, gA);
        #pragma unroll 1
        for (int jj = 0; jj < 9; ++jj) {
            PISSUE(2 * jj + 1, gB);
            PCOMBINE(2 * jj, gA, &cols[0][0][0]);   // waits oldest gathers
            asm volatile("s_waitcnt lgkmcnt(0)" ::: "memory");
            __builtin_amdgcn_s_barrier();           // barrier #2jj
            asm volatile("" ::: "memory");
            if (jj < 8) PISSUE(2 * jj + 2, gA);
            PCOMBINE(2 * jj + 1, gB, &cols[1][0][0]);
            asm volatile("s_waitcnt lgkmcnt(0)" ::: "memory");
            __builtin_amdgcn_s_barrier();           // barrier #2jj+1
            asm volatile("" ::: "memory");
        }
    } else {
        // ===================== CONSUMER (waves 4-7) =====================
        const int cw = wv - 4;            // 0..3
        const int o0 = cw * 64;           // 64 outputs per consumer wave
        const uint4* wvp = reinterpret_cast<const uint4*>(wTb);

        int ri[4];
        #pragma unroll
        for (int nt = 0; nt < 4; ++nt) {
            const int p = nt * 16 + l15;
            ri[nt] = p * 4 + (g ^ (p & 3) ^ ((p >> 2) & 3));
        }

        f32x4 acc[4][4];
        #pragma unroll
        for (int i = 0; i < 4; ++i)
            #pragma unroll
            for (int nt = 0; nt < 4; ++nt)
                acc[i][nt] = (f32x4){0.f, 0.f, 0.f, 0.f};

        auto CLOADA = [&](int cch, uint4 (&ap)[4][4]) {
            #pragma unroll
            for (int s = 0; s < 4; ++s) {
                const int kb = (cch * 4 + s) * 4 + g;
                #pragma unroll
                for (int i = 0; i < 4; ++i)
                    ap[s][i] = wvp[(size_t)kb * 256 + o0 + i * 16 + l15];
            }
        };

        auto CMFMA = [&](const uint* cbuf, const uint4 (&ap)[4][4]) {
            __builtin_amdgcn_s_setprio(1);
            #pragma unroll
            for (int s = 0; s < 4; ++s) {
                FragU a[4], bf[4];
                #pragma unroll
                for (int i = 0; i < 4; ++i) a[i].u = ap[s][i];
                #pragma unroll
                for (int nt = 0; nt < 4; ++nt)
                    bf[nt].u = reinterpret_cast<const uint4*>(cbuf + s * 1024)[ri[nt]];
                #pragma unroll
                for (int i = 0; i < 4; ++i)
                    #pragma unroll
                    for (int nt = 0; nt < 4; ++nt)
                        acc[i][nt] = __builtin_amdgcn_mfma_f32_16x16x32_f16(
                            a[i].h, bf[nt].h, acc[i][nt], 0, 0, 0);
            }
            __builtin_amdgcn_s_setprio(0);
        };

        uint4 aA[4][4], aB[4][4];
        CLOADA(0, aA);
        #pragma unroll 1
        for (int jj = 0; jj < 9; ++jj) {
            __builtin_amdgcn_s_barrier();           // barrier #2jj
            asm volatile("" ::: "memory");
            CLOADA(2 * jj + 1, aB);
            CMFMA(&cols[0][0][0], aA);
            __builtin_amdgcn_s_barrier();           // barrier #2jj+1
            asm volatile("" ::: "memory");
            if (jj < 8) CLOADA(2 * jj + 2, aA);
            CMFMA(&cols[1][0][0], aB);
        }

        float* ob = out + (size_t)b * On * PB;
        #pragma unroll
        for (int i = 0; i < 4; ++i)
            #pragma unroll
            for (int nt = 0; nt < 4; ++nt)
                #pragma unroll
                for (int j = 0; j < 4; ++j)
                    ob[((size_t)(o0 + i * 16 + g * 4 + j)) * PB
                       + p0 + nt * 16 + l15] = acc[i][nt][j];
    }
}

// ---------------------------------------------------------------- launch
extern "C" void kernel_launch(void* const* d_in, const int* in_sizes, int n_in,
                              void* d_out, int out_size, void* d_ws, size_t ws_size,
                              hipStream_t stream)
{
    const float* x    = (const float*)d_in[0];
    const float* offw = (const float*)d_in[1];
    const float* offb = (const float*)d_in[2];
    const float* modw = (const float*)d_in[3];
    const float* modb = (const float*)d_in[4];
    const float* wgt  = (const float*)d_in[5];
    float* out = (float*)d_out;

    char* ws = (char*)d_ws;
    float*  offm = (float*)ws;                   // 1,769,472 B
    ushort* wTb  = (ushort*)(ws + 1769472);      // 1,179,648 B
    ushort* owf  = (ushort*)(ws + 2949120);      // 147,456 B
    ushort* xhf  = (ushort*)(ws + 3244032);      // 8,388,608 B (fp16 NHWC)

    nhwcpack_kernel<<<dim3(512), dim3(256), 0, stream>>>(
        x, wgt, offw, modw, xhf, wTb, owf);
    offmask_tile_kernel<<<dim3(256), dim3(512), 0, stream>>>(
        xhf, offb, modb, owf, offm);
    deform_ws_kernel<<<dim3(256), dim3(512), 0, stream>>>(
        xhf, offm, wTb, out);
}

// Round 14
// 56.456 us; speedup vs baseline: 5.5849x; 1.0101x over previous
//
#include <hip/hip_runtime.h>
#include <math.h>

// Modulated deformable conv v2: B=4, C=256, H=W=64, O=256, K=3, PAD=1
// r31: r30 CORRECTNESS FIX. 16-wave WS kernel (8 producers + 8 consumers,
//      1024 threads, grid 256 -> 4 waves/SIMD). r30's bug: producer threads
//      wrote only 512 of 1024 uint4 ring slots (positions 32-63 stale).
//      Fix: each producer thread owns TWO positions (posT, posT+32) ->
//      slots w4a and w4a+128 (grp term invariant under pos+32, verified).
//      Ring/barrier chain = r29-verbatim. K1 verbatim; K2 = r27 tile.

constexpr int Bn = 4;
constexpr int Cn = 256;
constexpr int Hn = 64;
constexpr int Wn = 64;
constexpr int On = 256;
constexpr int PB = Hn * Wn;     // 4096
constexpr int NCH = 27;

typedef __attribute__((ext_vector_type(8))) _Float16 f16x8;  // 4 VGPRs
typedef __attribute__((ext_vector_type(2))) _Float16 f16x2;
typedef __attribute__((ext_vector_type(4))) float f32x4;
typedef __attribute__((ext_vector_type(4))) uint  uint4v;

union FragU { uint4 u; f16x8 h; };

__device__ inline ushort f2h(float f) {
    _Float16 h = (_Float16)f;
    return __builtin_bit_cast(ushort, h);
}
__device__ inline uint pkh(float a, float b) {
    return __builtin_bit_cast(uint, __builtin_amdgcn_cvt_pkrtz(a, b));
}
__device__ inline f16x2 u2h(uint u) { return __builtin_bit_cast(f16x2, u); }
__device__ inline uint h2u(f16x2 h) { return __builtin_bit_cast(uint, h); }

// ---------------------------------------------------------------- kernel 1
// NCHW fp32 -> NHWC fp16 plane + fp16 weight packs (r24b verbatim).
__global__ __launch_bounds__(256)
void nhwcpack_kernel(const float* __restrict__ x,
                     const float* __restrict__ w,
                     const float* __restrict__ offw,
                     const float* __restrict__ modw,
                     ushort* __restrict__ xhf,
                     ushort* __restrict__ wTb,
                     ushort* __restrict__ owf)
{
    const int bid = blockIdx.x;
    const int b = bid >> 7, seg = bid & 127;
    const int t = threadIdx.x;
    __shared__ float tile[32][257];

    const float* src = x + (size_t)b * Cn * PB + seg * 32;
    #pragma unroll 4
    for (int i = 0; i < 32; ++i) {
        const int idx = i * 256 + t;
        const int c = idx >> 5, p = idx & 31;
        tile[p][c] = src[(size_t)c * PB + p];
    }
    __syncthreads();

    const int pr = t & 127;
    const int r0 = (t >> 7) * 16;
    uint* dH = reinterpret_cast<uint*>(xhf + ((size_t)b * PB + seg * 32) * 256);
    #pragma unroll 4
    for (int i = 0; i < 16; ++i) {
        const int row = r0 + i;
        const float v0 = tile[row][2 * pr];
        const float v1 = tile[row][2 * pr + 1];
        dH[(size_t)row * 128 + pr] = pkh(v0, v1);
    }

    #pragma unroll 1
    for (int u = 0; u < 5; ++u) {
        int unit = (u < 4) ? bid * 4 + u : (bid < 256 ? 2048 + bid : -1);
        if (unit < 0) break;
        const int tap = unit >> 8, c = unit & 255;
        const int o = t;
        wTb[((size_t)(unit >> 3) * 256 + o) * 8 + (c & 7)] =
            f2h(w[((size_t)o * Cn + c) * 9 + tap]);
        if (o < 32) {
            float v = 0.f;
            if (o < 18)      v = offw[((size_t)o * Cn + c) * 9 + tap];
            else if (o < 27) v = modw[((size_t)(o - 18) * Cn + c) * 9 + tap];
            owf[((size_t)(unit >> 3) * 32 + o) * 8 + (c & 7)] = f2h(v);
        }
    }
}

// ---------------------------------------------------------------- kernel 2
// r27: offset/mask conv via LDS x-tile direct read (verbatim).
__global__ __launch_bounds__(512, 1)
void offmask_tile_kernel(const ushort* __restrict__ xhf,
                         const float* __restrict__ offb,
                         const float* __restrict__ modb,
                         const ushort* __restrict__ owf,
                         float* __restrict__ offm)
{
    const int hw = blockIdx.x;
    const int blk = (hw & 7) * 32 + (hw >> 3);
    const int b = blk >> 6, row = blk & 63;
    const int t = threadIdx.x;
    const int lane = t & 63;
    const int wv  = t >> 6;
    const int l15 = lane & 15;
    const int g   = lane >> 4;
    const int mt  = wv >> 2;
    const int nt  = wv & 3;

    __shared__ ushort xt[3 * 66 * 256];          // 101,376 B
    uint4* lds4 = reinterpret_cast<uint4*>(xt);  // 16B octets

    {
        const int c  = t >> 3;           // 0..63
        const int og = (t & 7) * 4;      // starting octet 0,4,..,28
        #pragma unroll 1
        for (int r = 0; r < 3; ++r) {
            const int ysrc = row - 1 + r;
            const int ci = c + 1;
            const int base = (r * 66 + ci) * 32;
            if (ysrc >= 0 && ysrc < Hn) {
                const uint4* src = reinterpret_cast<const uint4*>(
                    xhf + ((size_t)(b * PB + ysrc * 64 + c)) * 256);
                #pragma unroll
                for (int j = 0; j < 4; ++j) {
                    const int o = og + j;
                    lds4[base + (o ^ (ci & 7))] = src[o];
                }
            } else {
                const uint4 z = make_uint4(0u, 0u, 0u, 0u);
                #pragma unroll
                for (int j = 0; j < 4; ++j) {
                    const int o = og + j;
                    lds4[base + (o ^ (ci & 7))] = z;
                }
            }
        }
        if (t < 192) {
            const int r = t >> 6, idx = t & 63;
            const int ci = (idx >= 32) ? 65 : 0;
            const int o = idx & 31;
            lds4[(r * 66 + ci) * 32 + (o ^ (ci & 7))] =
                make_uint4(0u, 0u, 0u, 0u);
        }
    }
    __syncthreads();   // the ONLY barrier

    const uint4* owfV = reinterpret_cast<const uint4*>(owf);
    f32x4 acc = (f32x4){0.f, 0.f, 0.f, 0.f};
    const int pos = nt * 16 + l15;

    #pragma unroll 1
    for (int tap = 0; tap < 9; ++tap) {
        const int ty = tap / 3, tx = tap % 3;
        const int ci = pos + tx;
        const int cbase = (ty * 66 + ci) * 32;
        const int cx = ci & 7;

        uint4 aH[8];
        #pragma unroll
        for (int s = 0; s < 8; ++s) {
            const size_t kb = (size_t)((tap * 8 + s) * 4 + g) * 32 + mt * 16 + l15;
            aH[s] = owfV[kb];
        }

        #pragma unroll
        for (int s = 0; s < 8; ++s) {
            FragU aHH, bH;
            aHH.u = aH[s];
            bH.u = lds4[cbase + ((4 * s + g) ^ cx)];
            acc = __builtin_amdgcn_mfma_f32_16x16x32_f16(aHH.h, bH.h, acc, 0, 0, 0);
        }
    }

    #pragma unroll
    for (int j = 0; j < 4; ++j) {
        const int ch = mt * 16 + g * 4 + j;
        if (ch < NCH) {
            float v = acc[j];
            if (ch < 18) v += offb[ch];
            else         v = 2.f / (1.f + expf(-(v + modb[ch - 18])));
            offm[((size_t)(b * NCH + ch)) * PB + row * 64 + pos] = v;
        }
    }
}

// ---------------------------------------------------------------- kernel 3
// r31: 16-wave producer/consumer WS deform conv (coverage-fixed).
__global__ __launch_bounds__(1024, 1)
void deform_ws_kernel(const ushort* __restrict__ xhf,
                      const float* __restrict__ offm,
                      const ushort* __restrict__ wTb,
                      float* __restrict__ out)
{
    const int hw = blockIdx.x;
    const int blk = (hw & 7) * 32 + (hw >> 3);   // XCD swizzle (256 = 8*32)
    const int b = blk >> 6, row = blk & 63;
    const int p0 = row * 64;
    const int t = threadIdx.x;
    const int lane = t & 63;
    const int wv  = t >> 6;                      // 0..15
    const int l15 = lane & 15;
    const int g   = lane >> 4;

    __shared__ int4  s_off[576];       // [tap][pos 0..63]
    __shared__ uint4 s_wgt[576];       // duplicated-fp16 weight pairs
    __shared__ uint  cols[2][4][1024]; // 2-deep ring (32 KB)

    for (int ti = t; ti < 576; ti += 1024) {
        const int k = ti >> 6, pos = ti & 63;
        const int p = p0 + pos;
        const float dy = offm[((size_t)(b * NCH + 2 * k)) * PB + p];
        const float dx = offm[((size_t)(b * NCH + 2 * k + 1)) * PB + p];
        const float m  = offm[((size_t)(b * NCH + 18 + k)) * PB + p];
        const int ky = k / 3, kx = k % 3;
        const float py = dy + (float)(ky + row - 1);
        const float px = dx + (float)(kx + pos - 1);
        const float y0f = floorf(py), x0f = floorf(px);
        const float fy = py - y0f, fx = px - x0f;
        const int y0 = (int)y0f, x0i = (int)x0f;
        const int y1 = y0 + 1, x1 = x0i + 1;
        const bool vy0 = (y0 >= 0) && (y0 < Hn);
        const bool vy1 = (y1 >= 0) && (y1 < Hn);
        const bool vx0 = (x0i >= 0) && (x0i < Wn);
        const bool vx1 = (x1 >= 0) && (x1 < Wn);
        const int y0c = min(max(y0, 0), Hn - 1);
        const int y1c = min(max(y1, 0), Hn - 1);
        const int x0c = min(max(x0i, 0), Wn - 1);
        const int x1c = min(max(x1, 0), Wn - 1);
        s_off[ti] = make_int4(y0c * Wn + x0c, y0c * Wn + x1c,
                              y1c * Wn + x0c, y1c * Wn + x1c);
        const float w0 = (vy0 && vx0) ? (1.f - fy) * (1.f - fx) * m : 0.f;
        const float w1 = (vy0 && vx1) ? (1.f - fy) * fx * m : 0.f;
        const float w2 = (vy1 && vx0) ? fy * (1.f - fx) * m : 0.f;
        const float w3 = (vy1 && vx1) ? fy * fx * m : 0.f;
        s_wgt[ti] = make_uint4(pkh(w0, w0), pkh(w1, w1),
                               pkh(w2, w2), pkh(w3, w3));
    }
    __syncthreads();   // tap tables visible to all waves

    const ushort* xb = xhf + (size_t)b * PB * 256;

    if (wv < 8) {
        // ===================== PRODUCER (waves 0-7) =====================
        // 512 threads = 32 posT x 16 chq; each thread owns TWO positions
        // (posT and posT+32) -> 1024 uint4 units total = full ring coverage.
        const int chq  = t & 15;
        const int posT = t >> 4;          // 0..31
        const int sIdx = chq >> 2;
        const int grp  = (chq & 3) ^ (posT & 3) ^ ((posT >> 2) & 3);
        const int w4a  = posT * 4 + grp;  // pos posT+32 -> slot w4a + 128
        const ushort* xq = xb + 8 * chq;

        auto PISSUE = [&](int cch, uint4v (&gg)[2][4]) {
            const int tap = cch >> 1;
            const ushort* xcc = xq + (cch & 1) * 128;
            #pragma unroll
            for (int u = 0; u < 2; ++u) {
                const int4 o = s_off[tap * 64 + posT + u * 32];
                gg[u][0] = *reinterpret_cast<const uint4v*>(xcc + (size_t)o.x * 256);
                gg[u][1] = *reinterpret_cast<const uint4v*>(xcc + (size_t)o.y * 256);
                gg[u][2] = *reinterpret_cast<const uint4v*>(xcc + (size_t)o.z * 256);
                gg[u][3] = *reinterpret_cast<const uint4v*>(xcc + (size_t)o.w * 256);
            }
        };

        auto PCOMBINE = [&](int cch, const uint4v (&gg)[2][4], uint* cbuf) {
            const int tap = cch >> 1;
            uint4v* dst = reinterpret_cast<uint4v*>(cbuf + sIdx * 1024);
            #pragma unroll
            for (int u = 0; u < 2; ++u) {
                const uint4 wq = s_wgt[tap * 64 + posT + u * 32];
                uint pr[4];
                #pragma unroll
                for (int j = 0; j < 4; ++j) {
                    f16x2 v = u2h(gg[u][0][j]) * u2h(wq.x);
                    v += u2h(gg[u][1][j]) * u2h(wq.y);
                    v += u2h(gg[u][2][j]) * u2h(wq.z);
                    v += u2h(gg[u][3][j]) * u2h(wq.w);
                    pr[j] = h2u(v);
                }
                dst[w4a + u * 128] = (uint4v){pr[0], pr[1], pr[2], pr[3]};
            }
        };

        uint4v gA[2][4], gB[2][4];
        PISSUE(0, gA);
        #pragma unroll 1
        for (int jj = 0; jj < 9; ++jj) {
            PISSUE(2 * jj + 1, gB);
            PCOMBINE(2 * jj, gA, &cols[0][0][0]);   // waits oldest gathers
            asm volatile("s_waitcnt lgkmcnt(0)" ::: "memory");
            __builtin_amdgcn_s_barrier();           // barrier #2jj
            asm volatile("" ::: "memory");
            if (jj < 8) PISSUE(2 * jj + 2, gA);
            PCOMBINE(2 * jj + 1, gB, &cols[1][0][0]);
            asm volatile("s_waitcnt lgkmcnt(0)" ::: "memory");
            __builtin_amdgcn_s_barrier();           // barrier #2jj+1
            asm volatile("" ::: "memory");
        }
    } else {
        // ===================== CONSUMER (waves 8-15) ====================
        const int cw = wv - 8;            // 0..7
        const int o0 = cw * 32;           // 32 outputs per consumer wave
        const uint4* wvp = reinterpret_cast<const uint4*>(wTb);

        int ri[4];
        #pragma unroll
        for (int nt = 0; nt < 4; ++nt) {
            const int p = nt * 16 + l15;
            ri[nt] = p * 4 + (g ^ (p & 3) ^ ((p >> 2) & 3));
        }

        f32x4 acc[2][4];
        #pragma unroll
        for (int i = 0; i < 2; ++i)
            #pragma unroll
            for (int nt = 0; nt < 4; ++nt)
                acc[i][nt] = (f32x4){0.f, 0.f, 0.f, 0.f};

        auto CLOADA = [&](int cch, uint4 (&ap)[4][2]) {
            #pragma unroll
            for (int s = 0; s < 4; ++s) {
                const int kb = (cch * 4 + s) * 4 + g;
                ap[s][0] = wvp[(size_t)kb * 256 + o0 + l15];
                ap[s][1] = wvp[(size_t)kb * 256 + o0 + 16 + l15];
            }
        };

        auto CMFMA = [&](const uint* cbuf, const uint4 (&ap)[4][2]) {
            __builtin_amdgcn_s_setprio(1);
            #pragma unroll
            for (int s = 0; s < 4; ++s) {
                FragU a0, a1, bf[4];
                a0.u = ap[s][0]; a1.u = ap[s][1];
                #pragma unroll
                for (int nt = 0; nt < 4; ++nt)
                    bf[nt].u = reinterpret_cast<const uint4*>(cbuf + s * 1024)[ri[nt]];
                #pragma unroll
                for (int nt = 0; nt < 4; ++nt) {
                    acc[0][nt] = __builtin_amdgcn_mfma_f32_16x16x32_f16(
                        a0.h, bf[nt].h, acc[0][nt], 0, 0, 0);
                    acc[1][nt] = __builtin_amdgcn_mfma_f32_16x16x32_f16(
                        a1.h, bf[nt].h, acc[1][nt], 0, 0, 0);
                }
            }
            __builtin_amdgcn_s_setprio(0);
        };

        uint4 aA[4][2], aB[4][2];
        CLOADA(0, aA);
        #pragma unroll 1
        for (int jj = 0; jj < 9; ++jj) {
            __builtin_amdgcn_s_barrier();           // barrier #2jj
            asm volatile("" ::: "memory");
            CLOADA(2 * jj + 1, aB);
            CMFMA(&cols[0][0][0], aA);
            __builtin_amdgcn_s_barrier();           // barrier #2jj+1
            asm volatile("" ::: "memory");
            if (jj < 8) CLOADA(2 * jj + 2, aA);
            CMFMA(&cols[1][0][0], aB);
        }

        float* ob = out + (size_t)b * On * PB;
        #pragma unroll
        for (int i = 0; i < 2; ++i)
            #pragma unroll
            for (int nt = 0; nt < 4; ++nt)
                #pragma unroll
                for (int j = 0; j < 4; ++j)
                    ob[((size_t)(o0 + i * 16 + g * 4 + j)) * PB
                       + p0 + nt * 16 + l15] = acc[i][nt][j];
    }
}

// ---------------------------------------------------------------- launch
extern "C" void kernel_launch(void* const* d_in, const int* in_sizes, int n_in,
                              void* d_out, int out_size, void* d_ws, size_t ws_size,
                              hipStream_t stream)
{
    const float* x    = (const float*)d_in[0];
    const float* offw = (const float*)d_in[1];
    const float* offb = (const float*)d_in[2];
    const float* modw = (const float*)d_in[3];
    const float* modb = (const float*)d_in[4];
    const float* wgt  = (const float*)d_in[5];
    float* out = (float*)d_out;

    char* ws = (char*)d_ws;
    float*  offm = (float*)ws;                   // 1,769,472 B
    ushort* wTb  = (ushort*)(ws + 1769472);      // 1,179,648 B
    ushort* owf  = (ushort*)(ws + 2949120);      // 147,456 B
    ushort* xhf  = (ushort*)(ws + 3244032);      // 8,388,608 B (fp16 NHWC)

    nhwcpack_kernel<<<dim3(512), dim3(256), 0, stream>>>(
        x, wgt, offw, modw, xhf, wTb, owf);
    offmask_tile_kernel<<<dim3(256), dim3(512), 0, stream>>>(
        xhf, offb, modb, owf, offm);
    deform_ws_kernel<<<dim3(256), dim3(1024), 0, stream>>>(
        xhf, offm, wTb, out);
}

// Round 15
// 56.152 us; speedup vs baseline: 5.6151x; 1.0054x over previous
//
#include <hip/hip_runtime.h>
#include <math.h>

// Modulated deformable conv v2: B=4, C=256, H=W=64, O=256, K=3, PAD=1
// r32: K1 STREAMLINE (K3 frozen at r31 WS floor per pre-committed falsifier;
//      K2 = r27 tile verbatim). New K1 transpose: phase1 = 8x float4 global
//      loads + 8x ds_write_b128 into channel-major tile2[256][36] (stride
//      36 => all b128 ops 16B-aligned); phase2 = 4x ds_read_b128 + 8 pkh +
//      8 coalesced dword stores per 8 output words. ~3x fewer instructions
//      per word than the scalar r24b transpose. Weight-pack tail verbatim.

constexpr int Bn = 4;
constexpr int Cn = 256;
constexpr int Hn = 64;
constexpr int Wn = 64;
constexpr int On = 256;
constexpr int PB = Hn * Wn;     // 4096
constexpr int NCH = 27;

typedef __attribute__((ext_vector_type(8))) _Float16 f16x8;  // 4 VGPRs
typedef __attribute__((ext_vector_type(2))) _Float16 f16x2;
typedef __attribute__((ext_vector_type(4))) float f32x4;
typedef __attribute__((ext_vector_type(4))) uint  uint4v;

union FragU { uint4 u; f16x8 h; };

__device__ inline ushort f2h(float f) {
    _Float16 h = (_Float16)f;
    return __builtin_bit_cast(ushort, h);
}
__device__ inline uint pkh(float a, float b) {
    return __builtin_bit_cast(uint, __builtin_amdgcn_cvt_pkrtz(a, b));
}
__device__ inline f16x2 u2h(uint u) { return __builtin_bit_cast(f16x2, u); }
__device__ inline uint h2u(f16x2 h) { return __builtin_bit_cast(uint, h); }

// ---------------------------------------------------------------- kernel 1
// r32: wide-op NCHW fp32 -> NHWC fp16 transpose + weight packs.
__global__ __launch_bounds__(256)
void nhwcpack_kernel(const float* __restrict__ x,
                     const float* __restrict__ w,
                     const float* __restrict__ offw,
                     const float* __restrict__ modw,
                     ushort* __restrict__ xhf,
                     ushort* __restrict__ wTb,
                     ushort* __restrict__ owf)
{
    const int bid = blockIdx.x;
    const int b = bid >> 7, seg = bid & 127;
    const int t = threadIdx.x;
    __shared__ float tile2[256][36];   // channel-major; stride 36 -> 16B align

    // phase 1: 8x float4 loads (c = (t>>3)+32i, pos 4q..4q+3), b128 LDS writes
    {
        const int c0 = t >> 3;         // 0..31
        const int q  = t & 7;          // 0..7 -> positions 4q..4q+3
        const float* src = x + (size_t)b * Cn * PB + seg * 32 + 4 * q;
        #pragma unroll
        for (int i = 0; i < 8; ++i) {
            const int c = c0 + i * 32;
            const float4 v = *reinterpret_cast<const float4*>(src + (size_t)c * PB);
            *reinterpret_cast<float4*>(&tile2[c][4 * q]) = v;
        }
    }
    __syncthreads();

    // phase 2: pack channel pairs; 8 words (one pp-octet x one c2) per iter
    {
        const int c2 = t & 127;        // output word column
        const int ph = t >> 7;         // 0..1
        uint* dH = reinterpret_cast<uint*>(xhf + ((size_t)b * PB + seg * 32) * 256);
        #pragma unroll
        for (int r = 0; r < 2; ++r) {
            const int ppb = (ph + 2 * r) * 8;     // 0,8,16,24
            const float4 a0 = *reinterpret_cast<const float4*>(&tile2[2 * c2][ppb]);
            const float4 a1 = *reinterpret_cast<const float4*>(&tile2[2 * c2][ppb + 4]);
            const float4 b0 = *reinterpret_cast<const float4*>(&tile2[2 * c2 + 1][ppb]);
            const float4 b1 = *reinterpret_cast<const float4*>(&tile2[2 * c2 + 1][ppb + 4]);
            uint wds[8];
            wds[0] = pkh(a0.x, b0.x); wds[1] = pkh(a0.y, b0.y);
            wds[2] = pkh(a0.z, b0.z); wds[3] = pkh(a0.w, b0.w);
            wds[4] = pkh(a1.x, b1.x); wds[5] = pkh(a1.y, b1.y);
            wds[6] = pkh(a1.z, b1.z); wds[7] = pkh(a1.w, b1.w);
            #pragma unroll
            for (int j = 0; j < 8; ++j)
                dH[(size_t)(ppb + j) * 128 + c2] = wds[j];
        }
    }

    // weight-pack tail (r24b verbatim)
    #pragma unroll 1
    for (int u = 0; u < 5; ++u) {
        int unit = (u < 4) ? bid * 4 + u : (bid < 256 ? 2048 + bid : -1);
        if (unit < 0) break;
        const int tap = unit >> 8, c = unit & 255;
        const int o = t;
        wTb[((size_t)(unit >> 3) * 256 + o) * 8 + (c & 7)] =
            f2h(w[((size_t)o * Cn + c) * 9 + tap]);
        if (o < 32) {
            float v = 0.f;
            if (o < 18)      v = offw[((size_t)o * Cn + c) * 9 + tap];
            else if (o < 27) v = modw[((size_t)(o - 18) * Cn + c) * 9 + tap];
            owf[((size_t)(unit >> 3) * 32 + o) * 8 + (c & 7)] = f2h(v);
        }
    }
}

// ---------------------------------------------------------------- kernel 2
// r27: offset/mask conv via LDS x-tile direct read (verbatim).
__global__ __launch_bounds__(512, 1)
void offmask_tile_kernel(const ushort* __restrict__ xhf,
                         const float* __restrict__ offb,
                         const float* __restrict__ modb,
                         const ushort* __restrict__ owf,
                         float* __restrict__ offm)
{
    const int hw = blockIdx.x;
    const int blk = (hw & 7) * 32 + (hw >> 3);
    const int b = blk >> 6, row = blk & 63;
    const int t = threadIdx.x;
    const int lane = t & 63;
    const int wv  = t >> 6;
    const int l15 = lane & 15;
    const int g   = lane >> 4;
    const int mt  = wv >> 2;
    const int nt  = wv & 3;

    __shared__ ushort xt[3 * 66 * 256];          // 101,376 B
    uint4* lds4 = reinterpret_cast<uint4*>(xt);  // 16B octets

    {
        const int c  = t >> 3;           // 0..63
        const int og = (t & 7) * 4;      // starting octet 0,4,..,28
        #pragma unroll 1
        for (int r = 0; r < 3; ++r) {
            const int ysrc = row - 1 + r;
            const int ci = c + 1;
            const int base = (r * 66 + ci) * 32;
            if (ysrc >= 0 && ysrc < Hn) {
                const uint4* src = reinterpret_cast<const uint4*>(
                    xhf + ((size_t)(b * PB + ysrc * 64 + c)) * 256);
                #pragma unroll
                for (int j = 0; j < 4; ++j) {
                    const int o = og + j;
                    lds4[base + (o ^ (ci & 7))] = src[o];
                }
            } else {
                const uint4 z = make_uint4(0u, 0u, 0u, 0u);
                #pragma unroll
                for (int j = 0; j < 4; ++j) {
                    const int o = og + j;
                    lds4[base + (o ^ (ci & 7))] = z;
                }
            }
        }
        if (t < 192) {
            const int r = t >> 6, idx = t & 63;
            const int ci = (idx >= 32) ? 65 : 0;
            const int o = idx & 31;
            lds4[(r * 66 + ci) * 32 + (o ^ (ci & 7))] =
                make_uint4(0u, 0u, 0u, 0u);
        }
    }
    __syncthreads();   // the ONLY barrier

    const uint4* owfV = reinterpret_cast<const uint4*>(owf);
    f32x4 acc = (f32x4){0.f, 0.f, 0.f, 0.f};
    const int pos = nt * 16 + l15;

    #pragma unroll 1
    for (int tap = 0; tap < 9; ++tap) {
        const int ty = tap / 3, tx = tap % 3;
        const int ci = pos + tx;
        const int cbase = (ty * 66 + ci) * 32;
        const int cx = ci & 7;

        uint4 aH[8];
        #pragma unroll
        for (int s = 0; s < 8; ++s) {
            const size_t kb = (size_t)((tap * 8 + s) * 4 + g) * 32 + mt * 16 + l15;
            aH[s] = owfV[kb];
        }

        #pragma unroll
        for (int s = 0; s < 8; ++s) {
            FragU aHH, bH;
            aHH.u = aH[s];
            bH.u = lds4[cbase + ((4 * s + g) ^ cx)];
            acc = __builtin_amdgcn_mfma_f32_16x16x32_f16(aHH.h, bH.h, acc, 0, 0, 0);
        }
    }

    #pragma unroll
    for (int j = 0; j < 4; ++j) {
        const int ch = mt * 16 + g * 4 + j;
        if (ch < NCH) {
            float v = acc[j];
            if (ch < 18) v += offb[ch];
            else         v = 2.f / (1.f + expf(-(v + modb[ch - 18])));
            offm[((size_t)(b * NCH + ch)) * PB + row * 64 + pos] = v;
        }
    }
}

// ---------------------------------------------------------------- kernel 3
// r31: 16-wave producer/consumer WS deform conv (verbatim).
__global__ __launch_bounds__(1024, 1)
void deform_ws_kernel(const ushort* __restrict__ xhf,
                      const float* __restrict__ offm,
                      const ushort* __restrict__ wTb,
                      float* __restrict__ out)
{
    const int hw = blockIdx.x;
    const int blk = (hw & 7) * 32 + (hw >> 3);   // XCD swizzle (256 = 8*32)
    const int b = blk >> 6, row = blk & 63;
    const int p0 = row * 64;
    const int t = threadIdx.x;
    const int lane = t & 63;
    const int wv  = t >> 6;                      // 0..15
    const int l15 = lane & 15;
    const int g   = lane >> 4;

    __shared__ int4  s_off[576];       // [tap][pos 0..63]
    __shared__ uint4 s_wgt[576];       // duplicated-fp16 weight pairs
    __shared__ uint  cols[2][4][1024]; // 2-deep ring (32 KB)

    for (int ti = t; ti < 576; ti += 1024) {
        const int k = ti >> 6, pos = ti & 63;
        const int p = p0 + pos;
        const float dy = offm[((size_t)(b * NCH + 2 * k)) * PB + p];
        const float dx = offm[((size_t)(b * NCH + 2 * k + 1)) * PB + p];
        const float m  = offm[((size_t)(b * NCH + 18 + k)) * PB + p];
        const int ky = k / 3, kx = k % 3;
        const float py = dy + (float)(ky + row - 1);
        const float px = dx + (float)(kx + pos - 1);
        const float y0f = floorf(py), x0f = floorf(px);
        const float fy = py - y0f, fx = px - x0f;
        const int y0 = (int)y0f, x0i = (int)x0f;
        const int y1 = y0 + 1, x1 = x0i + 1;
        const bool vy0 = (y0 >= 0) && (y0 < Hn);
        const bool vy1 = (y1 >= 0) && (y1 < Hn);
        const bool vx0 = (x0i >= 0) && (x0i < Wn);
        const bool vx1 = (x1 >= 0) && (x1 < Wn);
        const int y0c = min(max(y0, 0), Hn - 1);
        const int y1c = min(max(y1, 0), Hn - 1);
        const int x0c = min(max(x0i, 0), Wn - 1);
        const int x1c = min(max(x1, 0), Wn - 1);
        s_off[ti] = make_int4(y0c * Wn + x0c, y0c * Wn + x1c,
                              y1c * Wn + x0c, y1c * Wn + x1c);
        const float w0 = (vy0 && vx0) ? (1.f - fy) * (1.f - fx) * m : 0.f;
        const float w1 = (vy0 && vx1) ? (1.f - fy) * fx * m : 0.f;
        const float w2 = (vy1 && vx0) ? fy * (1.f - fx) * m : 0.f;
        const float w3 = (vy1 && vx1) ? fy * fx * m : 0.f;
        s_wgt[ti] = make_uint4(pkh(w0, w0), pkh(w1, w1),
                               pkh(w2, w2), pkh(w3, w3));
    }
    __syncthreads();   // tap tables visible to all waves

    const ushort* xb = xhf + (size_t)b * PB * 256;

    if (wv < 8) {
        // ===================== PRODUCER (waves 0-7) =====================
        const int chq  = t & 15;
        const int posT = t >> 4;          // 0..31
        const int sIdx = chq >> 2;
        const int grp  = (chq & 3) ^ (posT & 3) ^ ((posT >> 2) & 3);
        const int w4a  = posT * 4 + grp;  // pos posT+32 -> slot w4a + 128
        const ushort* xq = xb + 8 * chq;

        auto PISSUE = [&](int cch, uint4v (&gg)[2][4]) {
            const int tap = cch >> 1;
            const ushort* xcc = xq + (cch & 1) * 128;
            #pragma unroll
            for (int u = 0; u < 2; ++u) {
                const int4 o = s_off[tap * 64 + posT + u * 32];
                gg[u][0] = *reinterpret_cast<const uint4v*>(xcc + (size_t)o.x * 256);
                gg[u][1] = *reinterpret_cast<const uint4v*>(xcc + (size_t)o.y * 256);
                gg[u][2] = *reinterpret_cast<const uint4v*>(xcc + (size_t)o.z * 256);
                gg[u][3] = *reinterpret_cast<const uint4v*>(xcc + (size_t)o.w * 256);
            }
        };

        auto PCOMBINE = [&](int cch, const uint4v (&gg)[2][4], uint* cbuf) {
            const int tap = cch >> 1;
            uint4v* dst = reinterpret_cast<uint4v*>(cbuf + sIdx * 1024);
            #pragma unroll
            for (int u = 0; u < 2; ++u) {
                const uint4 wq = s_wgt[tap * 64 + posT + u * 32];
                uint pr[4];
                #pragma unroll
                for (int j = 0; j < 4; ++j) {
                    f16x2 v = u2h(gg[u][0][j]) * u2h(wq.x);
                    v += u2h(gg[u][1][j]) * u2h(wq.y);
                    v += u2h(gg[u][2][j]) * u2h(wq.z);
                    v += u2h(gg[u][3][j]) * u2h(wq.w);
                    pr[j] = h2u(v);
                }
                dst[w4a + u * 128] = (uint4v){pr[0], pr[1], pr[2], pr[3]};
            }
        };

        uint4v gA[2][4], gB[2][4];
        PISSUE(0, gA);
        #pragma unroll 1
        for (int jj = 0; jj < 9; ++jj) {
            PISSUE(2 * jj + 1, gB);
            PCOMBINE(2 * jj, gA, &cols[0][0][0]);   // waits oldest gathers
            asm volatile("s_waitcnt lgkmcnt(0)" ::: "memory");
            __builtin_amdgcn_s_barrier();           // barrier #2jj
            asm volatile("" ::: "memory");
            if (jj < 8) PISSUE(2 * jj + 2, gA);
            PCOMBINE(2 * jj + 1, gB, &cols[1][0][0]);
            asm volatile("s_waitcnt lgkmcnt(0)" ::: "memory");
            __builtin_amdgcn_s_barrier();           // barrier #2jj+1
            asm volatile("" ::: "memory");
        }
    } else {
        // ===================== CONSUMER (waves 8-15) ====================
        const int cw = wv - 8;            // 0..7
        const int o0 = cw * 32;           // 32 outputs per consumer wave
        const uint4* wvp = reinterpret_cast<const uint4*>(wTb);

        int ri[4];
        #pragma unroll
        for (int nt = 0; nt < 4; ++nt) {
            const int p = nt * 16 + l15;
            ri[nt] = p * 4 + (g ^ (p & 3) ^ ((p >> 2) & 3));
        }

        f32x4 acc[2][4];
        #pragma unroll
        for (int i = 0; i < 2; ++i)
            #pragma unroll
            for (int nt = 0; nt < 4; ++nt)
                acc[i][nt] = (f32x4){0.f, 0.f, 0.f, 0.f};

        auto CLOADA = [&](int cch, uint4 (&ap)[4][2]) {
            #pragma unroll
            for (int s = 0; s < 4; ++s) {
                const int kb = (cch * 4 + s) * 4 + g;
                ap[s][0] = wvp[(size_t)kb * 256 + o0 + l15];
                ap[s][1] = wvp[(size_t)kb * 256 + o0 + 16 + l15];
            }
        };

        auto CMFMA = [&](const uint* cbuf, const uint4 (&ap)[4][2]) {
            __builtin_amdgcn_s_setprio(1);
            #pragma unroll
            for (int s = 0; s < 4; ++s) {
                FragU a0, a1, bf[4];
                a0.u = ap[s][0]; a1.u = ap[s][1];
                #pragma unroll
                for (int nt = 0; nt < 4; ++nt)
                    bf[nt].u = reinterpret_cast<const uint4*>(cbuf + s * 1024)[ri[nt]];
                #pragma unroll
                for (int nt = 0; nt < 4; ++nt) {
                    acc[0][nt] = __builtin_amdgcn_mfma_f32_16x16x32_f16(
                        a0.h, bf[nt].h, acc[0][nt], 0, 0, 0);
                    acc[1][nt] = __builtin_amdgcn_mfma_f32_16x16x32_f16(
                        a1.h, bf[nt].h, acc[1][nt], 0, 0, 0);
                }
            }
            __builtin_amdgcn_s_setprio(0);
        };

        uint4 aA[4][2], aB[4][2];
        CLOADA(0, aA);
        #pragma unroll 1
        for (int jj = 0; jj < 9; ++jj) {
            __builtin_amdgcn_s_barrier();           // barrier #2jj
            asm volatile("" ::: "memory");
            CLOADA(2 * jj + 1, aB);
            CMFMA(&cols[0][0][0], aA);
            __builtin_amdgcn_s_barrier();           // barrier #2jj+1
            asm volatile("" ::: "memory");
            if (jj < 8) CLOADA(2 * jj + 2, aA);
            CMFMA(&cols[1][0][0], aB);
        }

        float* ob = out + (size_t)b * On * PB;
        #pragma unroll
        for (int i = 0; i < 2; ++i)
            #pragma unroll
            for (int nt = 0; nt < 4; ++nt)
                #pragma unroll
                for (int j = 0; j < 4; ++j)
                    ob[((size_t)(o0 + i * 16 + g * 4 + j)) * PB
                       + p0 + nt * 16 + l15] = acc[i][nt][j];
    }
}

// ---------------------------------------------------------------- launch
extern "C" void kernel_launch(void* const* d_in, const int* in_sizes, int n_in,
                              void* d_out, int out_size, void* d_ws, size_t ws_size,
                              hipStream_t stream)
{
    const float* x    = (const float*)d_in[0];
    const float* offw = (const float*)d_in[1];
    const float* offb = (const float*)d_in[2];
    const float* modw = (const float*)d_in[3];
    const float* modb = (const float*)d_in[4];
    const float* wgt  = (const float*)d_in[5];
    float* out = (float*)d_out;

    char* ws = (char*)d_ws;
    float*  offm = (float*)ws;                   // 1,769,472 B
    ushort* wTb  = (ushort*)(ws + 1769472);      // 1,179,648 B
    ushort* owf  = (ushort*)(ws + 2949120);      // 147,456 B
    ushort* xhf  = (ushort*)(ws + 3244032);      // 8,388,608 B (fp16 NHWC)

    nhwcpack_kernel<<<dim3(512), dim3(256), 0, stream>>>(
        x, wgt, offw, modw, xhf, wTb, owf);
    offmask_tile_kernel<<<dim3(256), dim3(512), 0, stream>>>(
        xhf, offb, modb, owf, offm);
    deform_ws_kernel<<<dim3(256), dim3(1024), 0, stream>>>(
        xhf, offm, wTb, out);
}

// Round 16
// 52.265 us; speedup vs baseline: 6.0327x; 1.0744x over previous
//
#include <hip/hip_runtime.h>
#include <math.h>

// Modulated deformable conv v2: B=4, C=256, H=W=64, O=256, K=3, PAD=1
// r33: K3 BARRIER HALVING. Same r31 WS dataflow (8 producers + 8 consumers,
//      1024 threads, grid 256), but the cols ring is 4 chunk-slots (64 KB)
//      and the block barriers fire once per TWO K-chunks: 18 -> 9 barriers.
//      Producer: ISSUE(c+1),COMBINE(c),ISSUE(c+2),COMBINE(c+1),lgkm,barrier
//      (oldest-first vmcnt discipline preserved). Consumer: barrier,
//      MFMA(c),LOADA(c+2),MFMA(c+1),LOADA(c+3). Hazards re-traced: slot s
//      rewritten (c+4) only after the barrier following its consumption.
//      K1 = r32 wide-op transpose verbatim; K2 = r27 tile verbatim.

constexpr int Bn = 4;
constexpr int Cn = 256;
constexpr int Hn = 64;
constexpr int Wn = 64;
constexpr int On = 256;
constexpr int PB = Hn * Wn;     // 4096
constexpr int NCH = 27;

typedef __attribute__((ext_vector_type(8))) _Float16 f16x8;  // 4 VGPRs
typedef __attribute__((ext_vector_type(2))) _Float16 f16x2;
typedef __attribute__((ext_vector_type(4))) float f32x4;
typedef __attribute__((ext_vector_type(4))) uint  uint4v;

union FragU { uint4 u; f16x8 h; };

__device__ inline ushort f2h(float f) {
    _Float16 h = (_Float16)f;
    return __builtin_bit_cast(ushort, h);
}
__device__ inline uint pkh(float a, float b) {
    return __builtin_bit_cast(uint, __builtin_amdgcn_cvt_pkrtz(a, b));
}
__device__ inline f16x2 u2h(uint u) { return __builtin_bit_cast(f16x2, u); }
__device__ inline uint h2u(f16x2 h) { return __builtin_bit_cast(uint, h); }

// ---------------------------------------------------------------- kernel 1
// r32: wide-op NCHW fp32 -> NHWC fp16 transpose + weight packs (verbatim).
__global__ __launch_bounds__(256)
void nhwcpack_kernel(const float* __restrict__ x,
                     const float* __restrict__ w,
                     const float* __restrict__ offw,
                     const float* __restrict__ modw,
                     ushort* __restrict__ xhf,
                     ushort* __restrict__ wTb,
                     ushort* __restrict__ owf)
{
    const int bid = blockIdx.x;
    const int b = bid >> 7, seg = bid & 127;
    const int t = threadIdx.x;
    __shared__ float tile2[256][36];   // channel-major; stride 36 -> 16B align

    {
        const int c0 = t >> 3;         // 0..31
        const int q  = t & 7;          // 0..7 -> positions 4q..4q+3
        const float* src = x + (size_t)b * Cn * PB + seg * 32 + 4 * q;
        #pragma unroll
        for (int i = 0; i < 8; ++i) {
            const int c = c0 + i * 32;
            const float4 v = *reinterpret_cast<const float4*>(src + (size_t)c * PB);
            *reinterpret_cast<float4*>(&tile2[c][4 * q]) = v;
        }
    }
    __syncthreads();

    {
        const int c2 = t & 127;        // output word column
        const int ph = t >> 7;         // 0..1
        uint* dH = reinterpret_cast<uint*>(xhf + ((size_t)b * PB + seg * 32) * 256);
        #pragma unroll
        for (int r = 0; r < 2; ++r) {
            const int ppb = (ph + 2 * r) * 8;     // 0,8,16,24
            const float4 a0 = *reinterpret_cast<const float4*>(&tile2[2 * c2][ppb]);
            const float4 a1 = *reinterpret_cast<const float4*>(&tile2[2 * c2][ppb + 4]);
            const float4 b0 = *reinterpret_cast<const float4*>(&tile2[2 * c2 + 1][ppb]);
            const float4 b1 = *reinterpret_cast<const float4*>(&tile2[2 * c2 + 1][ppb + 4]);
            uint wds[8];
            wds[0] = pkh(a0.x, b0.x); wds[1] = pkh(a0.y, b0.y);
            wds[2] = pkh(a0.z, b0.z); wds[3] = pkh(a0.w, b0.w);
            wds[4] = pkh(a1.x, b1.x); wds[5] = pkh(a1.y, b1.y);
            wds[6] = pkh(a1.z, b1.z); wds[7] = pkh(a1.w, b1.w);
            #pragma unroll
            for (int j = 0; j < 8; ++j)
                dH[(size_t)(ppb + j) * 128 + c2] = wds[j];
        }
    }

    #pragma unroll 1
    for (int u = 0; u < 5; ++u) {
        int unit = (u < 4) ? bid * 4 + u : (bid < 256 ? 2048 + bid : -1);
        if (unit < 0) break;
        const int tap = unit >> 8, c = unit & 255;
        const int o = t;
        wTb[((size_t)(unit >> 3) * 256 + o) * 8 + (c & 7)] =
            f2h(w[((size_t)o * Cn + c) * 9 + tap]);
        if (o < 32) {
            float v = 0.f;
            if (o < 18)      v = offw[((size_t)o * Cn + c) * 9 + tap];
            else if (o < 27) v = modw[((size_t)(o - 18) * Cn + c) * 9 + tap];
            owf[((size_t)(unit >> 3) * 32 + o) * 8 + (c & 7)] = f2h(v);
        }
    }
}

// ---------------------------------------------------------------- kernel 2
// r27: offset/mask conv via LDS x-tile direct read (verbatim).
__global__ __launch_bounds__(512, 1)
void offmask_tile_kernel(const ushort* __restrict__ xhf,
                         const float* __restrict__ offb,
                         const float* __restrict__ modb,
                         const ushort* __restrict__ owf,
                         float* __restrict__ offm)
{
    const int hw = blockIdx.x;
    const int blk = (hw & 7) * 32 + (hw >> 3);
    const int b = blk >> 6, row = blk & 63;
    const int t = threadIdx.x;
    const int lane = t & 63;
    const int wv  = t >> 6;
    const int l15 = lane & 15;
    const int g   = lane >> 4;
    const int mt  = wv >> 2;
    const int nt  = wv & 3;

    __shared__ ushort xt[3 * 66 * 256];          // 101,376 B
    uint4* lds4 = reinterpret_cast<uint4*>(xt);  // 16B octets

    {
        const int c  = t >> 3;           // 0..63
        const int og = (t & 7) * 4;      // starting octet 0,4,..,28
        #pragma unroll 1
        for (int r = 0; r < 3; ++r) {
            const int ysrc = row - 1 + r;
            const int ci = c + 1;
            const int base = (r * 66 + ci) * 32;
            if (ysrc >= 0 && ysrc < Hn) {
                const uint4* src = reinterpret_cast<const uint4*>(
                    xhf + ((size_t)(b * PB + ysrc * 64 + c)) * 256);
                #pragma unroll
                for (int j = 0; j < 4; ++j) {
                    const int o = og + j;
                    lds4[base + (o ^ (ci & 7))] = src[o];
                }
            } else {
                const uint4 z = make_uint4(0u, 0u, 0u, 0u);
                #pragma unroll
                for (int j = 0; j < 4; ++j) {
                    const int o = og + j;
                    lds4[base + (o ^ (ci & 7))] = z;
                }
            }
        }
        if (t < 192) {
            const int r = t >> 6, idx = t & 63;
            const int ci = (idx >= 32) ? 65 : 0;
            const int o = idx & 31;
            lds4[(r * 66 + ci) * 32 + (o ^ (ci & 7))] =
                make_uint4(0u, 0u, 0u, 0u);
        }
    }
    __syncthreads();   // the ONLY barrier

    const uint4* owfV = reinterpret_cast<const uint4*>(owf);
    f32x4 acc = (f32x4){0.f, 0.f, 0.f, 0.f};
    const int pos = nt * 16 + l15;

    #pragma unroll 1
    for (int tap = 0; tap < 9; ++tap) {
        const int ty = tap / 3, tx = tap % 3;
        const int ci = pos + tx;
        const int cbase = (ty * 66 + ci) * 32;
        const int cx = ci & 7;

        uint4 aH[8];
        #pragma unroll
        for (int s = 0; s < 8; ++s) {
            const size_t kb = (size_t)((tap * 8 + s) * 4 + g) * 32 + mt * 16 + l15;
            aH[s] = owfV[kb];
        }

        #pragma unroll
        for (int s = 0; s < 8; ++s) {
            FragU aHH, bH;
            aHH.u = aH[s];
            bH.u = lds4[cbase + ((4 * s + g) ^ cx)];
            acc = __builtin_amdgcn_mfma_f32_16x16x32_f16(aHH.h, bH.h, acc, 0, 0, 0);
        }
    }

    #pragma unroll
    for (int j = 0; j < 4; ++j) {
        const int ch = mt * 16 + g * 4 + j;
        if (ch < NCH) {
            float v = acc[j];
            if (ch < 18) v += offb[ch];
            else         v = 2.f / (1.f + expf(-(v + modb[ch - 18])));
            offm[((size_t)(b * NCH + ch)) * PB + row * 64 + pos] = v;
        }
    }
}

// ---------------------------------------------------------------- kernel 3
// r33: 16-wave WS deform conv, 4-deep ring, barrier per 2 chunks.
__global__ __launch_bounds__(1024, 1)
void deform_ws_kernel(const ushort* __restrict__ xhf,
                      const float* __restrict__ offm,
                      const ushort* __restrict__ wTb,
                      float* __restrict__ out)
{
    const int hw = blockIdx.x;
    const int blk = (hw & 7) * 32 + (hw >> 3);   // XCD swizzle (256 = 8*32)
    const int b = blk >> 6, row = blk & 63;
    const int p0 = row * 64;
    const int t = threadIdx.x;
    const int lane = t & 63;
    const int wv  = t >> 6;                      // 0..15
    const int l15 = lane & 15;
    const int g   = lane >> 4;

    __shared__ int4  s_off[576];       // [tap][pos 0..63]
    __shared__ uint4 s_wgt[576];       // duplicated-fp16 weight pairs
    __shared__ uint  cols[4][4][1024]; // 4-deep ring (64 KB)

    for (int ti = t; ti < 576; ti += 1024) {
        const int k = ti >> 6, pos = ti & 63;
        const int p = p0 + pos;
        const float dy = offm[((size_t)(b * NCH + 2 * k)) * PB + p];
        const float dx = offm[((size_t)(b * NCH + 2 * k + 1)) * PB + p];
        const float m  = offm[((size_t)(b * NCH + 18 + k)) * PB + p];
        const int ky = k / 3, kx = k % 3;
        const float py = dy + (float)(ky + row - 1);
        const float px = dx + (float)(kx + pos - 1);
        const float y0f = floorf(py), x0f = floorf(px);
        const float fy = py - y0f, fx = px - x0f;
        const int y0 = (int)y0f, x0i = (int)x0f;
        const int y1 = y0 + 1, x1 = x0i + 1;
        const bool vy0 = (y0 >= 0) && (y0 < Hn);
        const bool vy1 = (y1 >= 0) && (y1 < Hn);
        const bool vx0 = (x0i >= 0) && (x0i < Wn);
        const bool vx1 = (x1 >= 0) && (x1 < Wn);
        const int y0c = min(max(y0, 0), Hn - 1);
        const int y1c = min(max(y1, 0), Hn - 1);
        const int x0c = min(max(x0i, 0), Wn - 1);
        const int x1c = min(max(x1, 0), Wn - 1);
        s_off[ti] = make_int4(y0c * Wn + x0c, y0c * Wn + x1c,
                              y1c * Wn + x0c, y1c * Wn + x1c);
        const float w0 = (vy0 && vx0) ? (1.f - fy) * (1.f - fx) * m : 0.f;
        const float w1 = (vy0 && vx1) ? (1.f - fy) * fx * m : 0.f;
        const float w2 = (vy1 && vx0) ? fy * (1.f - fx) * m : 0.f;
        const float w3 = (vy1 && vx1) ? fy * fx * m : 0.f;
        s_wgt[ti] = make_uint4(pkh(w0, w0), pkh(w1, w1),
                               pkh(w2, w2), pkh(w3, w3));
    }
    __syncthreads();   // tap tables visible to all waves

    const ushort* xb = xhf + (size_t)b * PB * 256;

    if (wv < 8) {
        // ===================== PRODUCER (waves 0-7) =====================
        const int chq  = t & 15;
        const int posT = t >> 4;          // 0..31
        const int sIdx = chq >> 2;
        const int grp  = (chq & 3) ^ (posT & 3) ^ ((posT >> 2) & 3);
        const int w4a  = posT * 4 + grp;  // pos posT+32 -> slot w4a + 128
        const ushort* xq = xb + 8 * chq;

        auto PISSUE = [&](int cch, uint4v (&gg)[2][4]) {
            const int tap = cch >> 1;
            const ushort* xcc = xq + (cch & 1) * 128;
            #pragma unroll
            for (int u = 0; u < 2; ++u) {
                const int4 o = s_off[tap * 64 + posT + u * 32];
                gg[u][0] = *reinterpret_cast<const uint4v*>(xcc + (size_t)o.x * 256);
                gg[u][1] = *reinterpret_cast<const uint4v*>(xcc + (size_t)o.y * 256);
                gg[u][2] = *reinterpret_cast<const uint4v*>(xcc + (size_t)o.z * 256);
                gg[u][3] = *reinterpret_cast<const uint4v*>(xcc + (size_t)o.w * 256);
            }
        };

        auto PCOMBINE = [&](int cch, const uint4v (&gg)[2][4], uint* cbuf) {
            const int tap = cch >> 1;
            uint4v* dst = reinterpret_cast<uint4v*>(cbuf + sIdx * 1024);
            #pragma unroll
            for (int u = 0; u < 2; ++u) {
                const uint4 wq = s_wgt[tap * 64 + posT + u * 32];
                uint pr[4];
                #pragma unroll
                for (int j = 0; j < 4; ++j) {
                    f16x2 v = u2h(gg[u][0][j]) * u2h(wq.x);
                    v += u2h(gg[u][1][j]) * u2h(wq.y);
                    v += u2h(gg[u][2][j]) * u2h(wq.z);
                    v += u2h(gg[u][3][j]) * u2h(wq.w);
                    pr[j] = h2u(v);
                }
                dst[w4a + u * 128] = (uint4v){pr[0], pr[1], pr[2], pr[3]};
            }
        };

        uint4v gA[2][4], gB[2][4];
        PISSUE(0, gA);
        #pragma unroll 1
        for (int jj = 0; jj < 9; ++jj) {
            const int sb = (jj & 1) * 2;            // slots sb, sb+1
            PISSUE(2 * jj + 1, gB);
            PCOMBINE(2 * jj, gA, &cols[sb][0][0]);  // waits oldest gathers
            if (jj < 8) PISSUE(2 * jj + 2, gA);     // after gA consumed
            PCOMBINE(2 * jj + 1, gB, &cols[sb + 1][0][0]);
            asm volatile("s_waitcnt lgkmcnt(0)" ::: "memory");
            __builtin_amdgcn_s_barrier();           // ONE barrier / 2 chunks
            asm volatile("" ::: "memory");
        }
    } else {
        // ===================== CONSUMER (waves 8-15) ====================
        const int cw = wv - 8;            // 0..7
        const int o0 = cw * 32;           // 32 outputs per consumer wave
        const uint4* wvp = reinterpret_cast<const uint4*>(wTb);

        int ri[4];
        #pragma unroll
        for (int nt = 0; nt < 4; ++nt) {
            const int p = nt * 16 + l15;
            ri[nt] = p * 4 + (g ^ (p & 3) ^ ((p >> 2) & 3));
        }

        f32x4 acc[2][4];
        #pragma unroll
        for (int i = 0; i < 2; ++i)
            #pragma unroll
            for (int nt = 0; nt < 4; ++nt)
                acc[i][nt] = (f32x4){0.f, 0.f, 0.f, 0.f};

        auto CLOADA = [&](int cch, uint4 (&ap)[4][2]) {
            #pragma unroll
            for (int s = 0; s < 4; ++s) {
                const int kb = (cch * 4 + s) * 4 + g;
                ap[s][0] = wvp[(size_t)kb * 256 + o0 + l15];
                ap[s][1] = wvp[(size_t)kb * 256 + o0 + 16 + l15];
            }
        };

        auto CMFMA = [&](const uint* cbuf, const uint4 (&ap)[4][2]) {
            __builtin_amdgcn_s_setprio(1);
            #pragma unroll
            for (int s = 0; s < 4; ++s) {
                FragU a0, a1, bf[4];
                a0.u = ap[s][0]; a1.u = ap[s][1];
                #pragma unroll
                for (int nt = 0; nt < 4; ++nt)
                    bf[nt].u = reinterpret_cast<const uint4*>(cbuf + s * 1024)[ri[nt]];
                #pragma unroll
                for (int nt = 0; nt < 4; ++nt) {
                    acc[0][nt] = __builtin_amdgcn_mfma_f32_16x16x32_f16(
                        a0.h, bf[nt].h, acc[0][nt], 0, 0, 0);
                    acc[1][nt] = __builtin_amdgcn_mfma_f32_16x16x32_f16(
                        a1.h, bf[nt].h, acc[1][nt], 0, 0, 0);
                }
            }
            __builtin_amdgcn_s_setprio(0);
        };

        uint4 aA[4][2], aB[4][2];
        CLOADA(0, aA);
        CLOADA(1, aB);
        #pragma unroll 1
        for (int jj = 0; jj < 9; ++jj) {
            const int sb = (jj & 1) * 2;
            __builtin_amdgcn_s_barrier();           // chunks 2jj,2jj+1 ready
            asm volatile("" ::: "memory");
            CMFMA(&cols[sb][0][0], aA);
            if (jj < 8) CLOADA(2 * jj + 2, aA);     // lands during next phase
            CMFMA(&cols[sb + 1][0][0], aB);
            if (jj < 8) CLOADA(2 * jj + 3, aB);
        }

        float* ob = out + (size_t)b * On * PB;
        #pragma unroll
        for (int i = 0; i < 2; ++i)
            #pragma unroll
            for (int nt = 0; nt < 4; ++nt)
                #pragma unroll
                for (int j = 0; j < 4; ++j)
                    ob[((size_t)(o0 + i * 16 + g * 4 + j)) * PB
                       + p0 + nt * 16 + l15] = acc[i][nt][j];
    }
}

// ---------------------------------------------------------------- launch
extern "C" void kernel_launch(void* const* d_in, const int* in_sizes, int n_in,
                              void* d_out, int out_size, void* d_ws, size_t ws_size,
                              hipStream_t stream)
{
    const float* x    = (const float*)d_in[0];
    const float* offw = (const float*)d_in[1];
    const float* offb = (const float*)d_in[2];
    const float* modw = (const float*)d_in[3];
    const float* modb = (const float*)d_in[4];
    const float* wgt  = (const float*)d_in[5];
    float* out = (float*)d_out;

    char* ws = (char*)d_ws;
    float*  offm = (float*)ws;                   // 1,769,472 B
    ushort* wTb  = (ushort*)(ws + 1769472);      // 1,179,648 B
    ushort* owf  = (ushort*)(ws + 2949120);      // 147,456 B
    ushort* xhf  = (ushort*)(ws + 3244032);      // 8,388,608 B (fp16 NHWC)

    nhwcpack_kernel<<<dim3(512), dim3(256), 0, stream>>>(
        x, wgt, offw, modw, xhf, wTb, owf);
    offmask_tile_kernel<<<dim3(256), dim3(512), 0, stream>>>(
        xhf, offb, modb, owf, offm);
    deform_ws_kernel<<<dim3(256), dim3(1024), 0, stream>>>(
        xhf, offm, wTb, out);
}